// Round 7
// baseline (447.619 us; speedup 1.0000x reference)
//
#include <hip/hip_runtime.h>
#include <hip/hip_bf16.h>
#include <math.h>

#define D_MODEL 1024
#define D_INNER 2048
#define DT_RANK 64
#define D_STATE 16
#define BSZ 2
#define SEQ 2048
#define NROW (BSZ * SEQ)    // 4096
#define NC 128              // scan time-chunks
#define CL (SEQ / NC)       // 16 steps per chunk
#define NCH (BSZ * D_INNER) // 4096 scan channels
#define KSPLIT 16           // GEMM B K-split
#define KCH (D_INNER / KSPLIT) // 128

typedef short bf16x8 __attribute__((ext_vector_type(8)));
typedef float f32x4 __attribute__((ext_vector_type(4)));

__device__ inline ushort f2bf(float f) {
    uint32_t u = __float_as_uint(f);
    return (ushort)((u + 0x7FFFu + ((u >> 16) & 1u)) >> 16);
}
__device__ inline float bf2f(ushort u) {
    return __uint_as_float(((uint32_t)u) << 16);
}

__device__ inline void gld_lds16(const void* g, void* l) {
    __builtin_amdgcn_global_load_lds(
        (__attribute__((address_space(1))) void*)g,
        (__attribute__((address_space(3))) void*)l, 16, 0, 0);
}

// ---------------- f32 -> bf16 convert (float4 -> ushort4) ----------------
__global__ __launch_bounds__(256) void cvt_bf16(const float* __restrict__ in,
                                                ushort* __restrict__ out) {
    int i = blockIdx.x * 256 + threadIdx.x;
    float4 v = ((const float4*)in)[i];
    ushort4 o;
    o.x = f2bf(v.x); o.y = f2bf(v.y); o.z = f2bf(v.z); o.w = f2bf(v.w);
    ((ushort4*)out)[i] = o;
}

// ---------------- LayerNorm -> bf16 output ----------------
__global__ __launch_bounds__(256) void ln_kernel(const float* __restrict__ x,
                                                 const float* __restrict__ w,
                                                 const float* __restrict__ b,
                                                 ushort* __restrict__ xn) {
    int row = blockIdx.x;
    int tid = threadIdx.x;
    const float4* xr = (const float4*)(x + (size_t)row * D_MODEL);
    float4 v = xr[tid];
    float s  = v.x + v.y + v.z + v.w;
    float ss = v.x * v.x + v.y * v.y + v.z * v.z + v.w * v.w;
#pragma unroll
    for (int o = 32; o > 0; o >>= 1) {
        s  += __shfl_down(s, o);
        ss += __shfl_down(ss, o);
    }
    __shared__ float red[8];
    int wid = tid >> 6, lane = tid & 63;
    if (lane == 0) { red[wid] = s; red[4 + wid] = ss; }
    __syncthreads();
    s  = red[0] + red[1] + red[2] + red[3];
    ss = red[4] + red[5] + red[6] + red[7];
    float mu  = s * (1.0f / D_MODEL);
    float var = ss * (1.0f / D_MODEL) - mu * mu;
    float inv = rsqrtf(var + 1e-5f);
    float4 wv = ((const float4*)w)[tid];
    float4 bv = ((const float4*)b)[tid];
    ushort4 o4;
    o4.x = f2bf((v.x - mu) * inv * wv.x + bv.x);
    o4.y = f2bf((v.y - mu) * inv * wv.y + bv.y);
    o4.z = f2bf((v.z - mu) * inv * wv.z + bv.z);
    o4.w = f2bf((v.w - mu) * inv * wv.w + bv.w);
    ((ushort4*)(xn + (size_t)row * D_MODEL))[tid] = o4;
}

// ---------------- bf16 MFMA GEMM: C[M,N] = A[M,K] * B[N,K]^T  (f32 out) -----------
// MODE 0: col<splitN -> C (f32); col>=splitN -> Zb (bf16, col-splitN), both ld=ldc
// MODE 2: C = acc + extra[row*ldc+col]   (residual)
template <int MODE>
__global__ __launch_bounds__(256) void gemm_mfma(
    const ushort* __restrict__ A, int lda,
    const ushort* __restrict__ B, int ldb,
    float* __restrict__ C, ushort* __restrict__ Zb, int ldc, int splitN,
    const float* __restrict__ extra, int K) {
    __shared__ ushort lds[2][2][128 * 32];
    int tid = threadIdx.x;
    int w = tid >> 6, lane = tid & 63;
    int bm = blockIdx.y * 128, bn = blockIdx.x * 128;
    int wr = w >> 1, wc = w & 1;

    int srow = tid >> 2, sseg = (tid & 3) << 3;
    const ushort* Abase = A + (size_t)(bm + srow) * lda + sseg;
    const ushort* Bbase = B + (size_t)(bn + srow) * ldb + sseg;
    int l0 = w * 512;

    int frow = lane & 15, fk = (lane >> 4) << 3;
    f32x4 acc[4][4] = {};

#define STAGE(buf, k0)                                                        \
    do {                                                                      \
        gld_lds16(Abase + (k0),                     &lds[buf][0][l0]);        \
        gld_lds16(Abase + (size_t)64 * lda + (k0),  &lds[buf][0][2048 + l0]); \
        gld_lds16(Bbase + (k0),                     &lds[buf][1][l0]);        \
        gld_lds16(Bbase + (size_t)64 * ldb + (k0),  &lds[buf][1][2048 + l0]); \
    } while (0)

    int nk = K >> 5;
    int cur = 0;
    STAGE(0, 0);
    __syncthreads();
    for (int kt = 0; kt < nk; ++kt) {
        if (kt + 1 < nk) STAGE(cur ^ 1, (kt + 1) << 5);
        bf16x8 a[4], b[4];
#pragma unroll
        for (int m = 0; m < 4; ++m)
            a[m] = *(const bf16x8*)&lds[cur][0][(wr * 64 + m * 16 + frow) * 32 + fk];
#pragma unroll
        for (int n = 0; n < 4; ++n)
            b[n] = *(const bf16x8*)&lds[cur][1][(wc * 64 + n * 16 + frow) * 32 + fk];
#pragma unroll
        for (int m = 0; m < 4; ++m)
#pragma unroll
            for (int n = 0; n < 4; ++n)
                acc[m][n] = __builtin_amdgcn_mfma_f32_16x16x32_bf16(a[m], b[n], acc[m][n], 0, 0, 0);
        __syncthreads();
        cur ^= 1;
    }
#undef STAGE

    int rbase = bm + wr * 64 + ((lane >> 4) << 2);
    int cbase = bn + wc * 64 + (lane & 15);
#pragma unroll
    for (int m = 0; m < 4; ++m) {
#pragma unroll
        for (int n = 0; n < 4; ++n) {
            int gc = cbase + n * 16;
#pragma unroll
            for (int j = 0; j < 4; ++j) {
                int gr = rbase + m * 16 + j;
                float v = acc[m][n][j];
                if (MODE == 0) {
                    if (gc < splitN) C[(size_t)gr * ldc + gc] = v;
                    else             Zb[(size_t)gr * ldc + (gc - splitN)] = f2bf(v);
                } else {
                    C[(size_t)gr * ldc + gc] = v + extra[(size_t)gr * ldc + gc];
                }
            }
        }
    }
}

// ---------------- Generic f32 tiled GEMM ----------------
#define BM 64
#define BN 64
#define BK 16
// MODE 1: C = softplus(acc + extra[col]); MODE 3: plain
template <int MODE>
__global__ __launch_bounds__(256) void gemm_tn(const float* __restrict__ A, int lda,
                                               const float* __restrict__ B, int ldb,
                                               float* __restrict__ C, int ldc,
                                               int M, int N, int K,
                                               const float* __restrict__ extra) {
    __shared__ float As[BK][BM];
    __shared__ float Bs[BK][BN];
    int bm = blockIdx.y * BM, bn = blockIdx.x * BN;
    int tid = threadIdx.x;
    int tx = tid & 15, ty = tid >> 4;
    int lrow = tid >> 2, lseg = (tid & 3) << 2;
    float acc[4][4] = {};

    for (int k0 = 0; k0 < K; k0 += BK) {
        float4 av = make_float4(0.f, 0.f, 0.f, 0.f);
        float4 bv = make_float4(0.f, 0.f, 0.f, 0.f);
        int agr = bm + lrow;
        if (agr < M) av = *(const float4*)(A + (size_t)agr * lda + k0 + lseg);
        int bgr = bn + lrow;
        if (bgr < N) bv = *(const float4*)(B + (size_t)bgr * ldb + k0 + lseg);
        __syncthreads();
        As[lseg + 0][lrow] = av.x; As[lseg + 1][lrow] = av.y;
        As[lseg + 2][lrow] = av.z; As[lseg + 3][lrow] = av.w;
        Bs[lseg + 0][lrow] = bv.x; Bs[lseg + 1][lrow] = bv.y;
        Bs[lseg + 2][lrow] = bv.z; Bs[lseg + 3][lrow] = bv.w;
        __syncthreads();
#pragma unroll
        for (int k = 0; k < BK; ++k) {
            float4 a4 = *(const float4*)&As[k][ty << 2];
            float4 b4 = *(const float4*)&Bs[k][tx << 2];
            float ar[4] = {a4.x, a4.y, a4.z, a4.w};
            float br[4] = {b4.x, b4.y, b4.z, b4.w};
#pragma unroll
            for (int i = 0; i < 4; ++i)
#pragma unroll
                for (int j = 0; j < 4; ++j) acc[i][j] += ar[i] * br[j];
        }
    }

#pragma unroll
    for (int i = 0; i < 4; ++i) {
        int gr = bm + (ty << 2) + i;
        if (gr >= M) continue;
#pragma unroll
        for (int j = 0; j < 4; ++j) {
            int gc = bn + (tx << 2) + j;
            if (gc >= N) continue;
            float v = acc[i][j];
            if (MODE == 1) {
                v += extra[gc];
                v = (v > 20.f) ? v : log1pf(expf(v));
                C[(size_t)gr * ldc + gc] = v;
            } else {
                C[(size_t)gr * ldc + gc] = v;
            }
        }
    }
}

// ---------------- GEMM B split-K: part[kc] = xc[:,kc*128:+128] @ x_proj^T ---------
__global__ __launch_bounds__(256) void gemm_b_split(const float* __restrict__ A,
                                                    const float* __restrict__ B,
                                                    float* __restrict__ part) {
    __shared__ float As[BK][BM];
    __shared__ float Bs[BK][BN];
    int bm = blockIdx.y * BM, bn = blockIdx.x * BN;
    int kc = blockIdx.z;
    int tid = threadIdx.x;
    int tx = tid & 15, ty = tid >> 4;
    int lrow = tid >> 2, lseg = (tid & 3) << 2;
    float acc[4][4] = {};

    int kbeg = kc * KCH;
    for (int k0 = kbeg; k0 < kbeg + KCH; k0 += BK) {
        float4 av = *(const float4*)(A + (size_t)(bm + lrow) * D_INNER + k0 + lseg);
        float4 bv = make_float4(0.f, 0.f, 0.f, 0.f);
        int bgr = bn + lrow;
        if (bgr < 96) bv = *(const float4*)(B + (size_t)bgr * D_INNER + k0 + lseg);
        __syncthreads();
        As[lseg + 0][lrow] = av.x; As[lseg + 1][lrow] = av.y;
        As[lseg + 2][lrow] = av.z; As[lseg + 3][lrow] = av.w;
        Bs[lseg + 0][lrow] = bv.x; Bs[lseg + 1][lrow] = bv.y;
        Bs[lseg + 2][lrow] = bv.z; Bs[lseg + 3][lrow] = bv.w;
        __syncthreads();
#pragma unroll
        for (int k = 0; k < BK; ++k) {
            float4 a4 = *(const float4*)&As[k][ty << 2];
            float4 b4 = *(const float4*)&Bs[k][tx << 2];
            float ar[4] = {a4.x, a4.y, a4.z, a4.w};
            float br[4] = {b4.x, b4.y, b4.z, b4.w};
#pragma unroll
            for (int i = 0; i < 4; ++i)
#pragma unroll
                for (int j = 0; j < 4; ++j) acc[i][j] += ar[i] * br[j];
        }
    }

    float* po = part + (size_t)kc * (NROW * 96);
#pragma unroll
    for (int i = 0; i < 4; ++i) {
        int gr = bm + (ty << 2) + i;
#pragma unroll
        for (int j = 0; j < 4; ++j) {
            int gc = bn + (tx << 2) + j;
            if (gc < 96) po[(size_t)gr * 96 + gc] = acc[i][j];
        }
    }
}

__global__ __launch_bounds__(256) void gemm_b_reduce(const float* __restrict__ part,
                                                     float* __restrict__ dbl) {
    int i = blockIdx.x * 256 + threadIdx.x;  // 393216
    float s = 0.f;
#pragma unroll
    for (int kc = 0; kc < KSPLIT; ++kc)
        s += part[(size_t)kc * (NROW * 96) + i];
    dbl[i] = s;
}

// ---------------- causal depthwise conv1d (k=4, left pad 3) + SiLU ----------------
__global__ __launch_bounds__(256) void conv_silu(const float* __restrict__ xin,
                                                 const float* __restrict__ w,
                                                 const float* __restrict__ cb,
                                                 float* __restrict__ xc) {
    int idx = blockIdx.x * 256 + threadIdx.x;
    int d4 = idx & 511;
    int m  = idx >> 9;
    int l  = m & (SEQ - 1);
    int d  = d4 << 2;
    float4 w0 = ((const float4*)w)[d + 0];
    float4 w1 = ((const float4*)w)[d + 1];
    float4 w2 = ((const float4*)w)[d + 2];
    float4 w3 = ((const float4*)w)[d + 3];
    float wr0[4] = {w0.x, w0.y, w0.z, w0.w};
    float wr1[4] = {w1.x, w1.y, w1.z, w1.w};
    float wr2[4] = {w2.x, w2.y, w2.z, w2.w};
    float wr3[4] = {w3.x, w3.y, w3.z, w3.w};
    float ax = cb[d], ay = cb[d + 1], az = cb[d + 2], aw = cb[d + 3];
#pragma unroll
    for (int j = 0; j < 4; ++j) {
        if (l - 3 + j >= 0) {
            float4 xv = *(const float4*)(xin + (size_t)(m - 3 + j) * D_INNER + d);
            ax += wr0[j] * xv.x;
            ay += wr1[j] * xv.y;
            az += wr2[j] * xv.z;
            aw += wr3[j] * xv.w;
        }
    }
    float4 o;
    o.x = ax / (1.f + __expf(-ax));
    o.y = ay / (1.f + __expf(-ay));
    o.z = az / (1.f + __expf(-az));
    o.w = aw / (1.f + __expf(-aw));
    *(float4*)(xc + (size_t)m * D_INNER + d) = o;
}

// ---------------- chunked selective scan, 16 states per thread --------------------
// thread g -> channel c = g & 4095, chunk k = g >> 12   (NC=128 chunks of CL=16)
#define EXP4(e, cj) \
    e.x = __expf(dt * cj.x); e.y = __expf(dt * cj.y); \
    e.z = __expf(dt * cj.z); e.w = __expf(dt * cj.w);
#define HUPD(hj, cj, Bv) { float4 e; EXP4(e, cj) \
    hj.x = e.x * hj.x + du * Bv.x; hj.y = e.y * hj.y + du * Bv.y; \
    hj.z = e.z * hj.z + du * Bv.z; hj.w = e.w * hj.w + du * Bv.w; }

__global__ __launch_bounds__(256) void scan_phase1(const float* __restrict__ delta,
                                                   const float* __restrict__ xc,
                                                   const float* __restrict__ dbl,
                                                   const float* __restrict__ A_log,
                                                   float* __restrict__ S,
                                                   float* __restrict__ sumdt) {
    int g = blockIdx.x * 256 + threadIdx.x;   // NCH*NC = 524288
    int c = g & (NCH - 1);
    int k = g >> 12;
    int d = c & (D_INNER - 1);
    int b = c >> 11;
    const float4* al = (const float4*)(A_log + d * D_STATE);
    float4 c0 = al[0], c1 = al[1], c2 = al[2], c3 = al[3];
    c0.x = -__expf(c0.x); c0.y = -__expf(c0.y); c0.z = -__expf(c0.z); c0.w = -__expf(c0.w);
    c1.x = -__expf(c1.x); c1.y = -__expf(c1.y); c1.z = -__expf(c1.z); c1.w = -__expf(c1.w);
    c2.x = -__expf(c2.x); c2.y = -__expf(c2.y); c2.z = -__expf(c2.z); c2.w = -__expf(c2.w);
    c3.x = -__expf(c3.x); c3.y = -__expf(c3.y); c3.z = -__expf(c3.z); c3.w = -__expf(c3.w);

    size_t r0 = (size_t)b * SEQ + (size_t)k * CL;
    const float* pd = delta + r0 * D_INNER + d;
    const float* pu = xc    + r0 * D_INNER + d;
    const float4* pB = (const float4*)(dbl + r0 * 96 + DT_RANK);
    float4 h0 = {}, h1 = {}, h2 = {}, h3 = {};
    float sdt = 0.f;
#pragma unroll 2
    for (int t = 0; t < CL; ++t) {
        float dt = *pd, u = *pu;
        float4 B0 = pB[0], B1 = pB[1], B2 = pB[2], B3 = pB[3];
        float du = dt * u;
        sdt += dt;
        HUPD(h0, c0, B0) HUPD(h1, c1, B1) HUPD(h2, c2, B2) HUPD(h3, c3, B3)
        pd += D_INNER; pu += D_INNER; pB += 24;
    }
    float4* So = (float4*)(S + ((size_t)g << 4));
    So[0] = h0; So[1] = h1; So[2] = h2; So[3] = h3;
    sumdt[g] = sdt;
}

// phase2: combine chunk summaries serially; hin written in-place over S
__global__ __launch_bounds__(256) void scan_phase2(float* __restrict__ S,
                                                   const float* __restrict__ sumdt,
                                                   const float* __restrict__ A_log) {
    int g = blockIdx.x * 256 + threadIdx.x;  // 65536
    int n = g & 15;
    int c = g >> 4;
    int d = c & (D_INNER - 1);
    float cn = -__expf(A_log[d * D_STATE + n]);
    float h = 0.f;
#pragma unroll 8
    for (int k = 0; k < NC; ++k) {
        int kc = (k << 12) | c;
        float P = __expf(sumdt[kc] * cn);
        size_t o = ((size_t)kc << 4) + n;
        float s = S[o];
        S[o] = h;              // hin for chunk k
        h = P * h + s;
    }
}

__global__ __launch_bounds__(256) void scan_phase3(const float* __restrict__ delta,
                                                   const float* __restrict__ xc,
                                                   const float* __restrict__ dbl,
                                                   const ushort* __restrict__ zb,
                                                   const float* __restrict__ A_log,
                                                   const float* __restrict__ Dp,
                                                   const float* __restrict__ hin,
                                                   ushort* __restrict__ y) {
    int g = blockIdx.x * 256 + threadIdx.x;
    int c = g & (NCH - 1);
    int k = g >> 12;
    int d = c & (D_INNER - 1);
    int b = c >> 11;
    const float4* al = (const float4*)(A_log + d * D_STATE);
    float4 c0 = al[0], c1 = al[1], c2 = al[2], c3 = al[3];
    c0.x = -__expf(c0.x); c0.y = -__expf(c0.y); c0.z = -__expf(c0.z); c0.w = -__expf(c0.w);
    c1.x = -__expf(c1.x); c1.y = -__expf(c1.y); c1.z = -__expf(c1.z); c1.w = -__expf(c1.w);
    c2.x = -__expf(c2.x); c2.y = -__expf(c2.y); c2.z = -__expf(c2.z); c2.w = -__expf(c2.w);
    c3.x = -__expf(c3.x); c3.y = -__expf(c3.y); c3.z = -__expf(c3.z); c3.w = -__expf(c3.w);
    float Dv = Dp[d];
    const float4* hi = (const float4*)(hin + ((size_t)g << 4));
    float4 h0 = hi[0], h1 = hi[1], h2 = hi[2], h3 = hi[3];

    size_t r0 = (size_t)b * SEQ + (size_t)k * CL;
    const float* pd = delta + r0 * D_INNER + d;
    const float* pu = xc    + r0 * D_INNER + d;
    const ushort* pz = zb   + r0 * D_INNER + d;
    ushort* py = y          + r0 * D_INNER + d;
    const float4* pB = (const float4*)(dbl + r0 * 96 + DT_RANK);
#pragma unroll 2
    for (int t = 0; t < CL; ++t) {
        float dt = *pd, u = *pu;
        float4 B0 = pB[0], B1 = pB[1], B2 = pB[2], B3 = pB[3];
        float4 C0 = pB[4], C1 = pB[5], C2 = pB[6], C3 = pB[7];
        float du = dt * u;
        HUPD(h0, c0, B0) HUPD(h1, c1, B1) HUPD(h2, c2, B2) HUPD(h3, c3, B3)
        float acc = h0.x * C0.x + h0.y * C0.y + h0.z * C0.z + h0.w * C0.w
                  + h1.x * C1.x + h1.y * C1.y + h1.z * C1.z + h1.w * C1.w
                  + h2.x * C2.x + h2.y * C2.y + h2.z * C2.z + h2.w * C2.w
                  + h3.x * C3.x + h3.y * C3.y + h3.z * C3.z + h3.w * C3.w;
        float zv = bf2f(*pz);
        float sz = zv / (1.f + __expf(-zv));
        *py = f2bf((acc + u * Dv) * sz);
        pd += D_INNER; pu += D_INNER; pz += D_INNER; py += D_INNER; pB += 24;
    }
}

extern "C" void kernel_launch(void* const* d_in, const int* in_sizes, int n_in,
                              void* d_out, int out_size, void* d_ws, size_t ws_size,
                              hipStream_t stream) {
    const float* x       = (const float*)d_in[0];
    const float* ln_w    = (const float*)d_in[1];
    const float* ln_b    = (const float*)d_in[2];
    const float* in_proj = (const float*)d_in[3];
    const float* conv_w  = (const float*)d_in[4];
    const float* conv_b  = (const float*)d_in[5];
    const float* x_proj  = (const float*)d_in[6];
    const float* dt_w    = (const float*)d_in[7];
    const float* dt_b    = (const float*)d_in[8];
    const float* A_log   = (const float*)d_in[9];
    const float* Dp      = (const float*)d_in[10];
    const float* out_w   = (const float*)d_in[11];
    float* out = (float*)d_out;

    char* ws = (char*)d_ws;
    const size_t MB = 1024ull * 1024ull;
    // Layout / lifetimes (NC=128):
    // [0,8)    xn_bf (LN -> GEMM A)
    // [8,16)   w_in_bf (cvt -> GEMM A)
    // [0,32)   Shin overlay 32 MB (phase1 -> phase2 -> phase3); valid: xn/w_in dead
    //          after GEMM A, x_in[16,32) dead after conv, part[16,40) dead after reduce
    // [16,48)  x_in f32 (GEMM A -> conv); then part [16,40) (split -> reduce);
    //          w_out_bf [41,45) (cvt -> GEMM D); sumdt [45,47) (ph1 -> ph2)
    // [48,64)  zbuf_bf (GEMM A -> phase3)
    // [64,96)  xc f32 (conv -> split, phase1/3)
    // [96,98)  dbl (reduce -> GEMM C, phase1/3)
    // [98,130) delta (GEMM C -> phase1/3)
    // [130,146) y_bf (phase3 -> GEMM D)
    ushort* xn_bf    = (ushort*)(ws);
    ushort* w_in_bf  = (ushort*)(ws + 8 * MB);
    float*  Shin     = (float*)(ws);              // 32 MB: NC*NCH*16 f32
    float*  x_in     = (float*)(ws + 16 * MB);
    float*  part     = (float*)(ws + 16 * MB);    // 24 MB: [16][4096][96] f32
    ushort* w_out_bf = (ushort*)(ws + 41 * MB);
    float*  sumdt    = (float*)(ws + 45 * MB);    // 2 MB: NC*NCH f32
    ushort* zbuf_bf  = (ushort*)(ws + 48 * MB);
    float*  xc       = (float*)(ws + 64 * MB);
    float*  dbl      = (float*)(ws + 96 * MB);
    float*  delta    = (float*)(ws + 98 * MB);
    ushort* y_bf     = (ushort*)(ws + 130 * MB);

    // 0. convert in_proj weights to bf16 (4096x1024)
    cvt_bf16<<<(2 * D_INNER * D_MODEL / 4) / 256, 256, 0, stream>>>(in_proj, w_in_bf);

    // 1. LayerNorm -> bf16
    ln_kernel<<<NROW, 256, 0, stream>>>(x, ln_w, ln_b, xn_bf);

    // 2. xz = xn @ in_proj^T  -> x_in (f32) | z (bf16)
    gemm_mfma<0><<<dim3(4096 / 128, NROW / 128), 256, 0, stream>>>(
        xn_bf, D_MODEL, w_in_bf, D_MODEL, x_in, zbuf_bf, D_INNER, D_INNER,
        nullptr, D_MODEL);

    // 3. causal depthwise conv + SiLU -> xc  (x_in dead after this)
    conv_silu<<<(NROW * (D_INNER / 4)) / 256, 256, 0, stream>>>(x_in, conv_w, conv_b, xc);

    // 3b. convert out_proj weights to bf16 ([41,45), x_in region, disjoint from part)
    cvt_bf16<<<(D_MODEL * D_INNER / 4) / 256, 256, 0, stream>>>(out_w, w_out_bf);

    // 4. dbl = xc @ x_proj^T  [4096,96] via split-K + reduce
    gemm_b_split<<<dim3(2, NROW / BM, KSPLIT), 256, 0, stream>>>(xc, x_proj, part);
    gemm_b_reduce<<<(NROW * 96) / 256, 256, 0, stream>>>(part, dbl);

    // 5. delta = softplus(dt @ dt_proj^T + dt_b)   [4096, 2048]
    gemm_tn<1><<<dim3(D_INNER / BN, NROW / BM), 256, 0, stream>>>(
        dbl, 96, dt_w, DT_RANK, delta, D_INNER, NROW, D_INNER, DT_RANK, dt_b);

    // 6. chunked selective scan (16 states/thread; skip & gate fused in phase 3)
    scan_phase1<<<(NCH * NC) / 256, 256, 0, stream>>>(
        delta, xc, dbl, A_log, Shin, sumdt);
    scan_phase2<<<(NCH * D_STATE) / 256, 256, 0, stream>>>(Shin, sumdt, A_log);
    scan_phase3<<<(NCH * NC) / 256, 256, 0, stream>>>(
        delta, xc, dbl, zbuf_bf, A_log, Dp, Shin, y_bf);

    // 7. out = y @ out_proj^T + x   (bf16 MFMA, residual epilogue)
    gemm_mfma<2><<<dim3(D_MODEL / 128, NROW / 128), 256, 0, stream>>>(
        y_bf, D_INNER, w_out_bf, D_INNER, out, nullptr, D_MODEL, 0,
        x, D_INNER);
}

// Round 9
// 408.643 us; speedup vs baseline: 1.0954x; 1.0954x over previous
//
#include <hip/hip_runtime.h>
#include <hip/hip_bf16.h>
#include <math.h>

#define D_MODEL 1024
#define D_INNER 2048
#define DT_RANK 64
#define D_STATE 16
#define BSZ 2
#define SEQ 2048
#define NROW (BSZ * SEQ)    // 4096
#define NC 128              // scan time-chunks
#define CL (SEQ / NC)       // 16 steps per chunk
#define NCH (BSZ * D_INNER) // 4096 scan channels
#define KSPLIT 16           // GEMM B K-split
#define KCH (D_INNER / KSPLIT) // 128

typedef short bf16x8 __attribute__((ext_vector_type(8)));
typedef float f32x4 __attribute__((ext_vector_type(4)));

__device__ inline ushort f2bf(float f) {
    uint32_t u = __float_as_uint(f);
    return (ushort)((u + 0x7FFFu + ((u >> 16) & 1u)) >> 16);
}
__device__ inline float bf2f(ushort u) {
    return __uint_as_float(((uint32_t)u) << 16);
}

__device__ inline void gld_lds16(const void* g, void* l) {
    __builtin_amdgcn_global_load_lds(
        (__attribute__((address_space(1))) void*)g,
        (__attribute__((address_space(3))) void*)l, 16, 0, 0);
}

// ---------------- f32 -> bf16 convert (float4 -> ushort4) ----------------
__global__ __launch_bounds__(256) void cvt_bf16(const float* __restrict__ in,
                                                ushort* __restrict__ out) {
    int i = blockIdx.x * 256 + threadIdx.x;
    float4 v = ((const float4*)in)[i];
    ushort4 o;
    o.x = f2bf(v.x); o.y = f2bf(v.y); o.z = f2bf(v.z); o.w = f2bf(v.w);
    ((ushort4*)out)[i] = o;
}

// ---------------- LayerNorm -> bf16 output ----------------
__global__ __launch_bounds__(256) void ln_kernel(const float* __restrict__ x,
                                                 const float* __restrict__ w,
                                                 const float* __restrict__ b,
                                                 ushort* __restrict__ xn) {
    int row = blockIdx.x;
    int tid = threadIdx.x;
    const float4* xr = (const float4*)(x + (size_t)row * D_MODEL);
    float4 v = xr[tid];
    float s  = v.x + v.y + v.z + v.w;
    float ss = v.x * v.x + v.y * v.y + v.z * v.z + v.w * v.w;
#pragma unroll
    for (int o = 32; o > 0; o >>= 1) {
        s  += __shfl_down(s, o);
        ss += __shfl_down(ss, o);
    }
    __shared__ float red[8];
    int wid = tid >> 6, lane = tid & 63;
    if (lane == 0) { red[wid] = s; red[4 + wid] = ss; }
    __syncthreads();
    s  = red[0] + red[1] + red[2] + red[3];
    ss = red[4] + red[5] + red[6] + red[7];
    float mu  = s * (1.0f / D_MODEL);
    float var = ss * (1.0f / D_MODEL) - mu * mu;
    float inv = rsqrtf(var + 1e-5f);
    float4 wv = ((const float4*)w)[tid];
    float4 bv = ((const float4*)b)[tid];
    ushort4 o4;
    o4.x = f2bf((v.x - mu) * inv * wv.x + bv.x);
    o4.y = f2bf((v.y - mu) * inv * wv.y + bv.y);
    o4.z = f2bf((v.z - mu) * inv * wv.z + bv.z);
    o4.w = f2bf((v.w - mu) * inv * wv.w + bv.w);
    ((ushort4*)(xn + (size_t)row * D_MODEL))[tid] = o4;
}

// ---------------- bf16 MFMA GEMM: C[M,N] = A[M,K] * B[N,K]^T  (f32 out) -----------
// MODE 0: col<splitN -> C (f32); col>=splitN -> Zb (bf16, col-splitN), both ld=ldc
// MODE 2: C = acc + extra[row*ldc+col]   (residual)
template <int MODE>
__global__ __launch_bounds__(256) void gemm_mfma(
    const ushort* __restrict__ A, int lda,
    const ushort* __restrict__ B, int ldb,
    float* __restrict__ C, ushort* __restrict__ Zb, int ldc, int splitN,
    const float* __restrict__ extra, int K) {
    __shared__ ushort lds[2][2][128 * 32];
    int tid = threadIdx.x;
    int w = tid >> 6, lane = tid & 63;
    int bm = blockIdx.y * 128, bn = blockIdx.x * 128;
    int wr = w >> 1, wc = w & 1;

    int srow = tid >> 2, sseg = (tid & 3) << 3;
    const ushort* Abase = A + (size_t)(bm + srow) * lda + sseg;
    const ushort* Bbase = B + (size_t)(bn + srow) * ldb + sseg;
    int l0 = w * 512;

    int frow = lane & 15, fk = (lane >> 4) << 3;
    f32x4 acc[4][4] = {};

#define STAGE(buf, k0)                                                        \
    do {                                                                      \
        gld_lds16(Abase + (k0),                     &lds[buf][0][l0]);        \
        gld_lds16(Abase + (size_t)64 * lda + (k0),  &lds[buf][0][2048 + l0]); \
        gld_lds16(Bbase + (k0),                     &lds[buf][1][l0]);        \
        gld_lds16(Bbase + (size_t)64 * ldb + (k0),  &lds[buf][1][2048 + l0]); \
    } while (0)

    int nk = K >> 5;
    int cur = 0;
    STAGE(0, 0);
    __syncthreads();
    for (int kt = 0; kt < nk; ++kt) {
        if (kt + 1 < nk) STAGE(cur ^ 1, (kt + 1) << 5);
        bf16x8 a[4], b[4];
#pragma unroll
        for (int m = 0; m < 4; ++m)
            a[m] = *(const bf16x8*)&lds[cur][0][(wr * 64 + m * 16 + frow) * 32 + fk];
#pragma unroll
        for (int n = 0; n < 4; ++n)
            b[n] = *(const bf16x8*)&lds[cur][1][(wc * 64 + n * 16 + frow) * 32 + fk];
#pragma unroll
        for (int m = 0; m < 4; ++m)
#pragma unroll
            for (int n = 0; n < 4; ++n)
                acc[m][n] = __builtin_amdgcn_mfma_f32_16x16x32_bf16(a[m], b[n], acc[m][n], 0, 0, 0);
        __syncthreads();
        cur ^= 1;
    }
#undef STAGE

    int rbase = bm + wr * 64 + ((lane >> 4) << 2);
    int cbase = bn + wc * 64 + (lane & 15);
#pragma unroll
    for (int m = 0; m < 4; ++m) {
#pragma unroll
        for (int n = 0; n < 4; ++n) {
            int gc = cbase + n * 16;
#pragma unroll
            for (int j = 0; j < 4; ++j) {
                int gr = rbase + m * 16 + j;
                float v = acc[m][n][j];
                if (MODE == 0) {
                    if (gc < splitN) C[(size_t)gr * ldc + gc] = v;
                    else             Zb[(size_t)gr * ldc + (gc - splitN)] = f2bf(v);
                } else {
                    C[(size_t)gr * ldc + gc] = v + extra[(size_t)gr * ldc + gc];
                }
            }
        }
    }
}

// ---------------- Generic f32 tiled GEMM ----------------
#define BM 64
#define BN 64
#define BK 16
// MODE 1: C = softplus(acc + extra[col]); MODE 3: plain
template <int MODE>
__global__ __launch_bounds__(256) void gemm_tn(const float* __restrict__ A, int lda,
                                               const float* __restrict__ B, int ldb,
                                               float* __restrict__ C, int ldc,
                                               int M, int N, int K,
                                               const float* __restrict__ extra) {
    __shared__ float As[BK][BM];
    __shared__ float Bs[BK][BN];
    int bm = blockIdx.y * BM, bn = blockIdx.x * BN;
    int tid = threadIdx.x;
    int tx = tid & 15, ty = tid >> 4;
    int lrow = tid >> 2, lseg = (tid & 3) << 2;
    float acc[4][4] = {};

    for (int k0 = 0; k0 < K; k0 += BK) {
        float4 av = make_float4(0.f, 0.f, 0.f, 0.f);
        float4 bv = make_float4(0.f, 0.f, 0.f, 0.f);
        int agr = bm + lrow;
        if (agr < M) av = *(const float4*)(A + (size_t)agr * lda + k0 + lseg);
        int bgr = bn + lrow;
        if (bgr < N) bv = *(const float4*)(B + (size_t)bgr * ldb + k0 + lseg);
        __syncthreads();
        As[lseg + 0][lrow] = av.x; As[lseg + 1][lrow] = av.y;
        As[lseg + 2][lrow] = av.z; As[lseg + 3][lrow] = av.w;
        Bs[lseg + 0][lrow] = bv.x; Bs[lseg + 1][lrow] = bv.y;
        Bs[lseg + 2][lrow] = bv.z; Bs[lseg + 3][lrow] = bv.w;
        __syncthreads();
#pragma unroll
        for (int k = 0; k < BK; ++k) {
            float4 a4 = *(const float4*)&As[k][ty << 2];
            float4 b4 = *(const float4*)&Bs[k][tx << 2];
            float ar[4] = {a4.x, a4.y, a4.z, a4.w};
            float br[4] = {b4.x, b4.y, b4.z, b4.w};
#pragma unroll
            for (int i = 0; i < 4; ++i)
#pragma unroll
                for (int j = 0; j < 4; ++j) acc[i][j] += ar[i] * br[j];
        }
    }

#pragma unroll
    for (int i = 0; i < 4; ++i) {
        int gr = bm + (ty << 2) + i;
        if (gr >= M) continue;
#pragma unroll
        for (int j = 0; j < 4; ++j) {
            int gc = bn + (tx << 2) + j;
            if (gc >= N) continue;
            float v = acc[i][j];
            if (MODE == 1) {
                v += extra[gc];
                v = (v > 20.f) ? v : log1pf(expf(v));
                C[(size_t)gr * ldc + gc] = v;
            } else {
                C[(size_t)gr * ldc + gc] = v;
            }
        }
    }
}

// ---------------- GEMM B split-K: part[kc] = xc[:,kc*128:+128] @ x_proj^T ---------
__global__ __launch_bounds__(256) void gemm_b_split(const float* __restrict__ A,
                                                    const float* __restrict__ B,
                                                    float* __restrict__ part) {
    __shared__ float As[BK][BM];
    __shared__ float Bs[BK][BN];
    int bm = blockIdx.y * BM, bn = blockIdx.x * BN;
    int kc = blockIdx.z;
    int tid = threadIdx.x;
    int tx = tid & 15, ty = tid >> 4;
    int lrow = tid >> 2, lseg = (tid & 3) << 2;
    float acc[4][4] = {};

    int kbeg = kc * KCH;
    for (int k0 = kbeg; k0 < kbeg + KCH; k0 += BK) {
        float4 av = *(const float4*)(A + (size_t)(bm + lrow) * D_INNER + k0 + lseg);
        float4 bv = make_float4(0.f, 0.f, 0.f, 0.f);
        int bgr = bn + lrow;
        if (bgr < 96) bv = *(const float4*)(B + (size_t)bgr * D_INNER + k0 + lseg);
        __syncthreads();
        As[lseg + 0][lrow] = av.x; As[lseg + 1][lrow] = av.y;
        As[lseg + 2][lrow] = av.z; As[lseg + 3][lrow] = av.w;
        Bs[lseg + 0][lrow] = bv.x; Bs[lseg + 1][lrow] = bv.y;
        Bs[lseg + 2][lrow] = bv.z; Bs[lseg + 3][lrow] = bv.w;
        __syncthreads();
#pragma unroll
        for (int k = 0; k < BK; ++k) {
            float4 a4 = *(const float4*)&As[k][ty << 2];
            float4 b4 = *(const float4*)&Bs[k][tx << 2];
            float ar[4] = {a4.x, a4.y, a4.z, a4.w};
            float br[4] = {b4.x, b4.y, b4.z, b4.w};
#pragma unroll
            for (int i = 0; i < 4; ++i)
#pragma unroll
                for (int j = 0; j < 4; ++j) acc[i][j] += ar[i] * br[j];
        }
    }

    float* po = part + (size_t)kc * (NROW * 96);
#pragma unroll
    for (int i = 0; i < 4; ++i) {
        int gr = bm + (ty << 2) + i;
#pragma unroll
        for (int j = 0; j < 4; ++j) {
            int gc = bn + (tx << 2) + j;
            if (gc < 96) po[(size_t)gr * 96 + gc] = acc[i][j];
        }
    }
}

__global__ __launch_bounds__(256) void gemm_b_reduce(const float* __restrict__ part,
                                                     float* __restrict__ dbl) {
    int i = blockIdx.x * 256 + threadIdx.x;  // 393216
    float s = 0.f;
#pragma unroll
    for (int kc = 0; kc < KSPLIT; ++kc)
        s += part[(size_t)kc * (NROW * 96) + i];
    dbl[i] = s;
}

// ---------------- causal depthwise conv1d (k=4, left pad 3) + SiLU ----------------
__global__ __launch_bounds__(256) void conv_silu(const float* __restrict__ xin,
                                                 const float* __restrict__ w,
                                                 const float* __restrict__ cb,
                                                 float* __restrict__ xc) {
    int idx = blockIdx.x * 256 + threadIdx.x;
    int d4 = idx & 511;
    int m  = idx >> 9;
    int l  = m & (SEQ - 1);
    int d  = d4 << 2;
    float4 w0 = ((const float4*)w)[d + 0];
    float4 w1 = ((const float4*)w)[d + 1];
    float4 w2 = ((const float4*)w)[d + 2];
    float4 w3 = ((const float4*)w)[d + 3];
    float wr0[4] = {w0.x, w0.y, w0.z, w0.w};
    float wr1[4] = {w1.x, w1.y, w1.z, w1.w};
    float wr2[4] = {w2.x, w2.y, w2.z, w2.w};
    float wr3[4] = {w3.x, w3.y, w3.z, w3.w};
    float ax = cb[d], ay = cb[d + 1], az = cb[d + 2], aw = cb[d + 3];
#pragma unroll
    for (int j = 0; j < 4; ++j) {
        if (l - 3 + j >= 0) {
            float4 xv = *(const float4*)(xin + (size_t)(m - 3 + j) * D_INNER + d);
            ax += wr0[j] * xv.x;
            ay += wr1[j] * xv.y;
            az += wr2[j] * xv.z;
            aw += wr3[j] * xv.w;
        }
    }
    float4 o;
    o.x = ax / (1.f + __expf(-ax));
    o.y = ay / (1.f + __expf(-ay));
    o.z = az / (1.f + __expf(-az));
    o.w = aw / (1.f + __expf(-aw));
    *(float4*)(xc + (size_t)m * D_INNER + d) = o;
}

// ---------------- chunked selective scan, 16 states per thread --------------------
// thread g -> channel c = g & 4095, chunk k = g >> 12   (NC=128 chunks of CL=16)
// Block (256 thr) covers 256 consecutive channels of ONE (b, chunk) -> B/C rows
// are block-uniform: stage them in LDS once, inner loop reads broadcast.
#define EXP4(e, cj) \
    e.x = __expf(dt * cj.x); e.y = __expf(dt * cj.y); \
    e.z = __expf(dt * cj.z); e.w = __expf(dt * cj.w);
#define HUPD(hj, cj, Bv) { float4 e; EXP4(e, cj) \
    hj.x = e.x * hj.x + du * Bv.x; hj.y = e.y * hj.y + du * Bv.y; \
    hj.z = e.z * hj.z + du * Bv.z; hj.w = e.w * hj.w + du * Bv.w; }

__global__ __launch_bounds__(256) void scan_phase1(const float* __restrict__ delta,
                                                   const float* __restrict__ xc,
                                                   const float* __restrict__ dbl,
                                                   const float* __restrict__ A_log,
                                                   float* __restrict__ S,
                                                   float* __restrict__ sumdt) {
    __shared__ float bs[CL][16];
    int tid = threadIdx.x;
    int g = blockIdx.x * 256 + tid;   // NCH*NC = 524288
    int c = g & (NCH - 1);
    int k = g >> 12;
    int d = c & (D_INNER - 1);
    int b = c >> 11;
    size_t r0 = (size_t)b * SEQ + (size_t)k * CL;  // block-uniform

    // stage B rows [CL][16]
    if (tid < CL * 4) {
        int t = tid >> 2, j = (tid & 3) << 2;
        *(float4*)&bs[t][j] = *(const float4*)(dbl + (r0 + t) * 96 + DT_RANK + j);
    }

    const float4* al = (const float4*)(A_log + d * D_STATE);
    float4 c0 = al[0], c1 = al[1], c2 = al[2], c3 = al[3];
    c0.x = -__expf(c0.x); c0.y = -__expf(c0.y); c0.z = -__expf(c0.z); c0.w = -__expf(c0.w);
    c1.x = -__expf(c1.x); c1.y = -__expf(c1.y); c1.z = -__expf(c1.z); c1.w = -__expf(c1.w);
    c2.x = -__expf(c2.x); c2.y = -__expf(c2.y); c2.z = -__expf(c2.z); c2.w = -__expf(c2.w);
    c3.x = -__expf(c3.x); c3.y = -__expf(c3.y); c3.z = -__expf(c3.z); c3.w = -__expf(c3.w);
    __syncthreads();

    const float* pd = delta + r0 * D_INNER + d;
    const float* pu = xc    + r0 * D_INNER + d;
    float4 h0 = {}, h1 = {}, h2 = {}, h3 = {};
    float sdt = 0.f;
#pragma unroll 4
    for (int t = 0; t < CL; ++t) {
        float dt = *pd, u = *pu;
        float4 B0 = *(const float4*)&bs[t][0];
        float4 B1 = *(const float4*)&bs[t][4];
        float4 B2 = *(const float4*)&bs[t][8];
        float4 B3 = *(const float4*)&bs[t][12];
        float du = dt * u;
        sdt += dt;
        HUPD(h0, c0, B0) HUPD(h1, c1, B1) HUPD(h2, c2, B2) HUPD(h3, c3, B3)
        pd += D_INNER; pu += D_INNER;
    }
    float4* So = (float4*)(S + ((size_t)g << 4));
    So[0] = h0; So[1] = h1; So[2] = h2; So[3] = h3;
    sumdt[g] = sdt;
}

// phase2: combine chunk summaries serially; hin written in-place over S
__global__ __launch_bounds__(256) void scan_phase2(float* __restrict__ S,
                                                   const float* __restrict__ sumdt,
                                                   const float* __restrict__ A_log) {
    int g = blockIdx.x * 256 + threadIdx.x;  // 65536
    int n = g & 15;
    int c = g >> 4;
    int d = c & (D_INNER - 1);
    float cn = -__expf(A_log[d * D_STATE + n]);
    float h = 0.f;
#pragma unroll 8
    for (int k = 0; k < NC; ++k) {
        int kc = (k << 12) | c;
        float P = __expf(sumdt[kc] * cn);
        size_t o = ((size_t)kc << 4) + n;
        float s = S[o];
        S[o] = h;              // hin for chunk k
        h = P * h + s;
    }
}

__global__ __launch_bounds__(256) void scan_phase3(const float* __restrict__ delta,
                                                   const float* __restrict__ xc,
                                                   const float* __restrict__ dbl,
                                                   const ushort* __restrict__ zb,
                                                   const float* __restrict__ A_log,
                                                   const float* __restrict__ Dp,
                                                   const float* __restrict__ hin,
                                                   ushort* __restrict__ y) {
    __shared__ float bcs[CL][32];
    int tid = threadIdx.x;
    int g = blockIdx.x * 256 + tid;
    int c = g & (NCH - 1);
    int k = g >> 12;
    int d = c & (D_INNER - 1);
    int b = c >> 11;
    size_t r0 = (size_t)b * SEQ + (size_t)k * CL;  // block-uniform

    // stage B|C rows [CL][32]
    if (tid < CL * 8) {
        int t = tid >> 3, j = (tid & 7) << 2;
        *(float4*)&bcs[t][j] = *(const float4*)(dbl + (r0 + t) * 96 + DT_RANK + j);
    }

    const float4* al = (const float4*)(A_log + d * D_STATE);
    float4 c0 = al[0], c1 = al[1], c2 = al[2], c3 = al[3];
    c0.x = -__expf(c0.x); c0.y = -__expf(c0.y); c0.z = -__expf(c0.z); c0.w = -__expf(c0.w);
    c1.x = -__expf(c1.x); c1.y = -__expf(c1.y); c1.z = -__expf(c1.z); c1.w = -__expf(c1.w);
    c2.x = -__expf(c2.x); c2.y = -__expf(c2.y); c2.z = -__expf(c2.z); c2.w = -__expf(c2.w);
    c3.x = -__expf(c3.x); c3.y = -__expf(c3.y); c3.z = -__expf(c3.z); c3.w = -__expf(c3.w);
    float Dv = Dp[d];
    const float4* hi = (const float4*)(hin + ((size_t)g << 4));
    float4 h0 = hi[0], h1 = hi[1], h2 = hi[2], h3 = hi[3];
    __syncthreads();

    const float* pd = delta + r0 * D_INNER + d;
    const float* pu = xc    + r0 * D_INNER + d;
    const ushort* pz = zb   + r0 * D_INNER + d;
    ushort* py = y          + r0 * D_INNER + d;
#pragma unroll 4
    for (int t = 0; t < CL; ++t) {
        float dt = *pd, u = *pu;
        float4 B0 = *(const float4*)&bcs[t][0];
        float4 B1 = *(const float4*)&bcs[t][4];
        float4 B2 = *(const float4*)&bcs[t][8];
        float4 B3 = *(const float4*)&bcs[t][12];
        float4 C0 = *(const float4*)&bcs[t][16];
        float4 C1 = *(const float4*)&bcs[t][20];
        float4 C2 = *(const float4*)&bcs[t][24];
        float4 C3 = *(const float4*)&bcs[t][28];
        float du = dt * u;
        HUPD(h0, c0, B0) HUPD(h1, c1, B1) HUPD(h2, c2, B2) HUPD(h3, c3, B3)
        float acc = h0.x * C0.x + h0.y * C0.y + h0.z * C0.z + h0.w * C0.w
                  + h1.x * C1.x + h1.y * C1.y + h1.z * C1.z + h1.w * C1.w
                  + h2.x * C2.x + h2.y * C2.y + h2.z * C2.z + h2.w * C2.w
                  + h3.x * C3.x + h3.y * C3.y + h3.z * C3.z + h3.w * C3.w;
        float zv = bf2f(*pz);
        float sz = zv / (1.f + __expf(-zv));
        *py = f2bf((acc + u * Dv) * sz);
        pd += D_INNER; pu += D_INNER; pz += D_INNER; py += D_INNER;
    }
}

extern "C" void kernel_launch(void* const* d_in, const int* in_sizes, int n_in,
                              void* d_out, int out_size, void* d_ws, size_t ws_size,
                              hipStream_t stream) {
    const float* x       = (const float*)d_in[0];
    const float* ln_w    = (const float*)d_in[1];
    const float* ln_b    = (const float*)d_in[2];
    const float* in_proj = (const float*)d_in[3];
    const float* conv_w  = (const float*)d_in[4];
    const float* conv_b  = (const float*)d_in[5];
    const float* x_proj  = (const float*)d_in[6];
    const float* dt_w    = (const float*)d_in[7];
    const float* dt_b    = (const float*)d_in[8];
    const float* A_log   = (const float*)d_in[9];
    const float* Dp      = (const float*)d_in[10];
    const float* out_w   = (const float*)d_in[11];
    float* out = (float*)d_out;

    char* ws = (char*)d_ws;
    const size_t MB = 1024ull * 1024ull;
    // Layout / lifetimes (NC=128):
    // [0,8)    xn_bf (LN -> GEMM A)
    // [8,16)   w_in_bf (cvt -> GEMM A)
    // [0,32)   Shin overlay 32 MB (phase1 -> phase2 -> phase3)
    // [16,48)  x_in f32 (GEMM A -> conv); then part [16,40) (split -> reduce);
    //          w_out_bf [41,45) (cvt -> GEMM D); sumdt [45,47) (ph1 -> ph2)
    // [48,64)  zbuf_bf (GEMM A -> phase3)
    // [64,96)  xc f32 (conv -> split, phase1/3)
    // [96,98)  dbl (reduce -> GEMM C, phase1/3)
    // [98,130) delta (GEMM C -> phase1/3)
    // [130,146) y_bf (phase3 -> GEMM D)
    ushort* xn_bf    = (ushort*)(ws);
    ushort* w_in_bf  = (ushort*)(ws + 8 * MB);
    float*  Shin     = (float*)(ws);              // 32 MB: NC*NCH*16 f32
    float*  x_in     = (float*)(ws + 16 * MB);
    float*  part     = (float*)(ws + 16 * MB);    // 24 MB: [16][4096][96] f32
    ushort* w_out_bf = (ushort*)(ws + 41 * MB);
    float*  sumdt    = (float*)(ws + 45 * MB);    // 2 MB: NC*NCH f32
    ushort* zbuf_bf  = (ushort*)(ws + 48 * MB);
    float*  xc       = (float*)(ws + 64 * MB);
    float*  dbl      = (float*)(ws + 96 * MB);
    float*  delta    = (float*)(ws + 98 * MB);
    ushort* y_bf     = (ushort*)(ws + 130 * MB);

    // 0. convert in_proj weights to bf16 (4096x1024)
    cvt_bf16<<<(2 * D_INNER * D_MODEL / 4) / 256, 256, 0, stream>>>(in_proj, w_in_bf);

    // 1. LayerNorm -> bf16
    ln_kernel<<<NROW, 256, 0, stream>>>(x, ln_w, ln_b, xn_bf);

    // 2. xz = xn @ in_proj^T  -> x_in (f32) | z (bf16)
    gemm_mfma<0><<<dim3(4096 / 128, NROW / 128), 256, 0, stream>>>(
        xn_bf, D_MODEL, w_in_bf, D_MODEL, x_in, zbuf_bf, D_INNER, D_INNER,
        nullptr, D_MODEL);

    // 3. causal depthwise conv + SiLU -> xc  (x_in dead after this)
    conv_silu<<<(NROW * (D_INNER / 4)) / 256, 256, 0, stream>>>(x_in, conv_w, conv_b, xc);

    // 3b. convert out_proj weights to bf16 ([41,45), disjoint from part)
    cvt_bf16<<<(D_MODEL * D_INNER / 4) / 256, 256, 0, stream>>>(out_w, w_out_bf);

    // 4. dbl = xc @ x_proj^T  [4096,96] via split-K + reduce
    gemm_b_split<<<dim3(2, NROW / BM, KSPLIT), 256, 0, stream>>>(xc, x_proj, part);
    gemm_b_reduce<<<(NROW * 96) / 256, 256, 0, stream>>>(part, dbl);

    // 5. delta = softplus(dt @ dt_proj^T + dt_b)   [4096, 2048]
    gemm_tn<1><<<dim3(D_INNER / BN, NROW / BM), 256, 0, stream>>>(
        dbl, 96, dt_w, DT_RANK, delta, D_INNER, NROW, D_INNER, DT_RANK, dt_b);

    // 6. chunked selective scan (16 states/thread; skip & gate fused in phase 3)
    scan_phase1<<<(NCH * NC) / 256, 256, 0, stream>>>(
        delta, xc, dbl, A_log, Shin, sumdt);
    scan_phase2<<<(NCH * D_STATE) / 256, 256, 0, stream>>>(Shin, sumdt, A_log);
    scan_phase3<<<(NCH * NC) / 256, 256, 0, stream>>>(
        delta, xc, dbl, zbuf_bf, A_log, Dp, Shin, y_bf);

    // 7. out = y @ out_proj^T + x   (bf16 MFMA, residual epilogue)
    gemm_mfma<2><<<dim3(D_MODEL / 128, NROW / 128), 256, 0, stream>>>(
        y_bf, D_INNER, w_out_bf, D_INNER, out, nullptr, D_MODEL, 0,
        x, D_INNER);
}

// Round 10
// 396.199 us; speedup vs baseline: 1.1298x; 1.0314x over previous
//
#include <hip/hip_runtime.h>
#include <hip/hip_bf16.h>
#include <math.h>

#define D_MODEL 1024
#define D_INNER 2048
#define DT_RANK 64
#define D_STATE 16
#define BSZ 2
#define SEQ 2048
#define NROW (BSZ * SEQ)    // 4096
#define NC 128              // scan time-chunks
#define CL (SEQ / NC)       // 16 steps per chunk
#define NCH (BSZ * D_INNER) // 4096 scan channels
#define KSPLIT 16           // GEMM B K-split
#define KCH (D_INNER / KSPLIT) // 128

typedef short bf16x8 __attribute__((ext_vector_type(8)));
typedef float f32x4 __attribute__((ext_vector_type(4)));

__device__ inline ushort f2bf(float f) {
    uint32_t u = __float_as_uint(f);
    return (ushort)((u + 0x7FFFu + ((u >> 16) & 1u)) >> 16);
}
__device__ inline float bf2f(ushort u) {
    return __uint_as_float(((uint32_t)u) << 16);
}

__device__ inline void gld_lds16(const void* g, void* l) {
    __builtin_amdgcn_global_load_lds(
        (__attribute__((address_space(1))) void*)g,
        (__attribute__((address_space(3))) void*)l, 16, 0, 0);
}

// ---------------- f32 -> bf16 convert (float4 -> ushort4) ----------------
__global__ __launch_bounds__(256) void cvt_bf16(const float* __restrict__ in,
                                                ushort* __restrict__ out) {
    int i = blockIdx.x * 256 + threadIdx.x;
    float4 v = ((const float4*)in)[i];
    ushort4 o;
    o.x = f2bf(v.x); o.y = f2bf(v.y); o.z = f2bf(v.z); o.w = f2bf(v.w);
    ((ushort4*)out)[i] = o;
}

// ---------------- LayerNorm -> bf16 output ----------------
__global__ __launch_bounds__(256) void ln_kernel(const float* __restrict__ x,
                                                 const float* __restrict__ w,
                                                 const float* __restrict__ b,
                                                 ushort* __restrict__ xn) {
    int row = blockIdx.x;
    int tid = threadIdx.x;
    const float4* xr = (const float4*)(x + (size_t)row * D_MODEL);
    float4 v = xr[tid];
    float s  = v.x + v.y + v.z + v.w;
    float ss = v.x * v.x + v.y * v.y + v.z * v.z + v.w * v.w;
#pragma unroll
    for (int o = 32; o > 0; o >>= 1) {
        s  += __shfl_down(s, o);
        ss += __shfl_down(ss, o);
    }
    __shared__ float red[8];
    int wid = tid >> 6, lane = tid & 63;
    if (lane == 0) { red[wid] = s; red[4 + wid] = ss; }
    __syncthreads();
    s  = red[0] + red[1] + red[2] + red[3];
    ss = red[4] + red[5] + red[6] + red[7];
    float mu  = s * (1.0f / D_MODEL);
    float var = ss * (1.0f / D_MODEL) - mu * mu;
    float inv = rsqrtf(var + 1e-5f);
    float4 wv = ((const float4*)w)[tid];
    float4 bv = ((const float4*)b)[tid];
    ushort4 o4;
    o4.x = f2bf((v.x - mu) * inv * wv.x + bv.x);
    o4.y = f2bf((v.y - mu) * inv * wv.y + bv.y);
    o4.z = f2bf((v.z - mu) * inv * wv.z + bv.z);
    o4.w = f2bf((v.w - mu) * inv * wv.w + bv.w);
    ((ushort4*)(xn + (size_t)row * D_MODEL))[tid] = o4;
}

// ---------------- bf16 MFMA GEMM: C = A[M,K] * B[N,K]^T -----------------
// MODE 0: split bf16 store: col<splitN -> Z0, else Z1 (col-splitN), ld=ldc
// MODE 1: Z0 = bf16(softplus(acc + extra[col]))
// MODE 2: C(f32) = acc + extra[row*ldc+col]   (residual)
template <int MODE>
__global__ __launch_bounds__(256) void gemm_mfma(
    const ushort* __restrict__ A, int lda,
    const ushort* __restrict__ B, int ldb,
    float* __restrict__ C, ushort* __restrict__ Z0, ushort* __restrict__ Z1,
    int ldc, int splitN, const float* __restrict__ extra, int K) {
    __shared__ ushort lds[2][2][128 * 32];
    int tid = threadIdx.x;
    int w = tid >> 6, lane = tid & 63;
    int bm = blockIdx.y * 128, bn = blockIdx.x * 128;
    int wr = w >> 1, wc = w & 1;

    int srow = tid >> 2, sseg = (tid & 3) << 3;
    const ushort* Abase = A + (size_t)(bm + srow) * lda + sseg;
    const ushort* Bbase = B + (size_t)(bn + srow) * ldb + sseg;
    int l0 = w * 512;

    int frow = lane & 15, fk = (lane >> 4) << 3;
    f32x4 acc[4][4] = {};

#define STAGE(buf, k0)                                                        \
    do {                                                                      \
        gld_lds16(Abase + (k0),                     &lds[buf][0][l0]);        \
        gld_lds16(Abase + (size_t)64 * lda + (k0),  &lds[buf][0][2048 + l0]); \
        gld_lds16(Bbase + (k0),                     &lds[buf][1][l0]);        \
        gld_lds16(Bbase + (size_t)64 * ldb + (k0),  &lds[buf][1][2048 + l0]); \
    } while (0)

    int nk = K >> 5;
    int cur = 0;
    STAGE(0, 0);
    __syncthreads();
    for (int kt = 0; kt < nk; ++kt) {
        if (kt + 1 < nk) STAGE(cur ^ 1, (kt + 1) << 5);
        bf16x8 a[4], b[4];
#pragma unroll
        for (int m = 0; m < 4; ++m)
            a[m] = *(const bf16x8*)&lds[cur][0][(wr * 64 + m * 16 + frow) * 32 + fk];
#pragma unroll
        for (int n = 0; n < 4; ++n)
            b[n] = *(const bf16x8*)&lds[cur][1][(wc * 64 + n * 16 + frow) * 32 + fk];
#pragma unroll
        for (int m = 0; m < 4; ++m)
#pragma unroll
            for (int n = 0; n < 4; ++n)
                acc[m][n] = __builtin_amdgcn_mfma_f32_16x16x32_bf16(a[m], b[n], acc[m][n], 0, 0, 0);
        __syncthreads();
        cur ^= 1;
    }
#undef STAGE

    int rbase = bm + wr * 64 + ((lane >> 4) << 2);
    int cbase = bn + wc * 64 + (lane & 15);
#pragma unroll
    for (int m = 0; m < 4; ++m) {
#pragma unroll
        for (int n = 0; n < 4; ++n) {
            int gc = cbase + n * 16;
#pragma unroll
            for (int j = 0; j < 4; ++j) {
                int gr = rbase + m * 16 + j;
                float v = acc[m][n][j];
                if (MODE == 0) {
                    if (gc < splitN) Z0[(size_t)gr * ldc + gc] = f2bf(v);
                    else             Z1[(size_t)gr * ldc + (gc - splitN)] = f2bf(v);
                } else if (MODE == 1) {
                    v += extra[gc];
                    v = (v > 20.f) ? v : log1pf(__expf(v));
                    Z0[(size_t)gr * ldc + gc] = f2bf(v);
                } else {
                    C[(size_t)gr * ldc + gc] = v + extra[(size_t)gr * ldc + gc];
                }
            }
        }
    }
}

// ---------------- GEMM B split-K: part[kc] = xc_bf[:,kc*128:+128] @ x_proj^T ------
#define BM 64
#define BN 64
#define BK 16
__global__ __launch_bounds__(256) void gemm_b_split(const ushort* __restrict__ A,
                                                    const float* __restrict__ B,
                                                    float* __restrict__ part) {
    __shared__ float As[BK][BM];
    __shared__ float Bs[BK][BN];
    int bm = blockIdx.y * BM, bn = blockIdx.x * BN;
    int kc = blockIdx.z;
    int tid = threadIdx.x;
    int tx = tid & 15, ty = tid >> 4;
    int lrow = tid >> 2, lseg = (tid & 3) << 2;
    float acc[4][4] = {};

    int kbeg = kc * KCH;
    for (int k0 = kbeg; k0 < kbeg + KCH; k0 += BK) {
        ushort4 au = *(const ushort4*)(A + (size_t)(bm + lrow) * D_INNER + k0 + lseg);
        float4 av = make_float4(bf2f(au.x), bf2f(au.y), bf2f(au.z), bf2f(au.w));
        float4 bv = make_float4(0.f, 0.f, 0.f, 0.f);
        int bgr = bn + lrow;
        if (bgr < 96) bv = *(const float4*)(B + (size_t)bgr * D_INNER + k0 + lseg);
        __syncthreads();
        As[lseg + 0][lrow] = av.x; As[lseg + 1][lrow] = av.y;
        As[lseg + 2][lrow] = av.z; As[lseg + 3][lrow] = av.w;
        Bs[lseg + 0][lrow] = bv.x; Bs[lseg + 1][lrow] = bv.y;
        Bs[lseg + 2][lrow] = bv.z; Bs[lseg + 3][lrow] = bv.w;
        __syncthreads();
#pragma unroll
        for (int k = 0; k < BK; ++k) {
            float4 a4 = *(const float4*)&As[k][ty << 2];
            float4 b4 = *(const float4*)&Bs[k][tx << 2];
            float ar[4] = {a4.x, a4.y, a4.z, a4.w};
            float br[4] = {b4.x, b4.y, b4.z, b4.w};
#pragma unroll
            for (int i = 0; i < 4; ++i)
#pragma unroll
                for (int j = 0; j < 4; ++j) acc[i][j] += ar[i] * br[j];
        }
    }

    float* po = part + (size_t)kc * (NROW * 96);
#pragma unroll
    for (int i = 0; i < 4; ++i) {
        int gr = bm + (ty << 2) + i;
#pragma unroll
        for (int j = 0; j < 4; ++j) {
            int gc = bn + (tx << 2) + j;
            if (gc < 96) po[(size_t)gr * 96 + gc] = acc[i][j];
        }
    }
}

__global__ __launch_bounds__(256) void gemm_b_reduce(const float* __restrict__ part,
                                                     ushort* __restrict__ dbl) {
    int i = blockIdx.x * 256 + threadIdx.x;  // 393216
    float s = 0.f;
#pragma unroll
    for (int kc = 0; kc < KSPLIT; ++kc)
        s += part[(size_t)kc * (NROW * 96) + i];
    dbl[i] = f2bf(s);
}

// ---------------- causal depthwise conv1d (k=4) + SiLU, bf16 in/out ---------------
__global__ __launch_bounds__(256) void conv_silu(const ushort* __restrict__ xin,
                                                 const float* __restrict__ w,
                                                 const float* __restrict__ cb,
                                                 ushort* __restrict__ xc) {
    int idx = blockIdx.x * 256 + threadIdx.x;
    int d4 = idx & 511;
    int m  = idx >> 9;
    int l  = m & (SEQ - 1);
    int d  = d4 << 2;
    float4 w0 = ((const float4*)w)[d + 0];
    float4 w1 = ((const float4*)w)[d + 1];
    float4 w2 = ((const float4*)w)[d + 2];
    float4 w3 = ((const float4*)w)[d + 3];
    float wr0[4] = {w0.x, w0.y, w0.z, w0.w};
    float wr1[4] = {w1.x, w1.y, w1.z, w1.w};
    float wr2[4] = {w2.x, w2.y, w2.z, w2.w};
    float wr3[4] = {w3.x, w3.y, w3.z, w3.w};
    float ax = cb[d], ay = cb[d + 1], az = cb[d + 2], aw = cb[d + 3];
#pragma unroll
    for (int j = 0; j < 4; ++j) {
        if (l - 3 + j >= 0) {
            ushort4 xu = *(const ushort4*)(xin + (size_t)(m - 3 + j) * D_INNER + d);
            ax += wr0[j] * bf2f(xu.x);
            ay += wr1[j] * bf2f(xu.y);
            az += wr2[j] * bf2f(xu.z);
            aw += wr3[j] * bf2f(xu.w);
        }
    }
    ushort4 o;
    o.x = f2bf(ax / (1.f + __expf(-ax)));
    o.y = f2bf(ay / (1.f + __expf(-ay)));
    o.z = f2bf(az / (1.f + __expf(-az)));
    o.w = f2bf(aw / (1.f + __expf(-aw)));
    *(ushort4*)(xc + (size_t)m * D_INNER + d) = o;
}

// ---------------- chunked selective scan, 16 states per thread --------------------
// thread g -> channel c = g & 4095, chunk k = g >> 12 (NC=128, CL=16)
// Block-uniform (b,chunk): B/C rows staged in LDS (converted bf16->f32).
#define EXP4(e, cj) \
    e.x = __expf(dt * cj.x); e.y = __expf(dt * cj.y); \
    e.z = __expf(dt * cj.z); e.w = __expf(dt * cj.w);
#define HUPD(hj, cj, Bv) { float4 e; EXP4(e, cj) \
    hj.x = e.x * hj.x + du * Bv.x; hj.y = e.y * hj.y + du * Bv.y; \
    hj.z = e.z * hj.z + du * Bv.z; hj.w = e.w * hj.w + du * Bv.w; }

__global__ __launch_bounds__(256) void scan_phase1(const ushort* __restrict__ delta,
                                                   const ushort* __restrict__ xc,
                                                   const ushort* __restrict__ dbl,
                                                   const float* __restrict__ A_log,
                                                   float* __restrict__ S,
                                                   float* __restrict__ sumdt) {
    __shared__ float bs[CL][16];
    int tid = threadIdx.x;
    int g = blockIdx.x * 256 + tid;   // NCH*NC = 524288
    int c = g & (NCH - 1);
    int k = g >> 12;
    int d = c & (D_INNER - 1);
    int b = c >> 11;
    size_t r0 = (size_t)b * SEQ + (size_t)k * CL;  // block-uniform

    if (tid < CL * 4) {
        int t = tid >> 2, j = (tid & 3) << 2;
        ushort4 u4 = *(const ushort4*)(dbl + (r0 + t) * 96 + DT_RANK + j);
        bs[t][j + 0] = bf2f(u4.x); bs[t][j + 1] = bf2f(u4.y);
        bs[t][j + 2] = bf2f(u4.z); bs[t][j + 3] = bf2f(u4.w);
    }

    const float4* al = (const float4*)(A_log + d * D_STATE);
    float4 c0 = al[0], c1 = al[1], c2 = al[2], c3 = al[3];
    c0.x = -__expf(c0.x); c0.y = -__expf(c0.y); c0.z = -__expf(c0.z); c0.w = -__expf(c0.w);
    c1.x = -__expf(c1.x); c1.y = -__expf(c1.y); c1.z = -__expf(c1.z); c1.w = -__expf(c1.w);
    c2.x = -__expf(c2.x); c2.y = -__expf(c2.y); c2.z = -__expf(c2.z); c2.w = -__expf(c2.w);
    c3.x = -__expf(c3.x); c3.y = -__expf(c3.y); c3.z = -__expf(c3.z); c3.w = -__expf(c3.w);
    __syncthreads();

    const ushort* pd = delta + r0 * D_INNER + d;
    const ushort* pu = xc    + r0 * D_INNER + d;
    float4 h0 = {}, h1 = {}, h2 = {}, h3 = {};
    float sdt = 0.f;
#pragma unroll 4
    for (int t = 0; t < CL; ++t) {
        float dt = bf2f(*pd), u = bf2f(*pu);
        float4 B0 = *(const float4*)&bs[t][0];
        float4 B1 = *(const float4*)&bs[t][4];
        float4 B2 = *(const float4*)&bs[t][8];
        float4 B3 = *(const float4*)&bs[t][12];
        float du = dt * u;
        sdt += dt;
        HUPD(h0, c0, B0) HUPD(h1, c1, B1) HUPD(h2, c2, B2) HUPD(h3, c3, B3)
        pd += D_INNER; pu += D_INNER;
    }
    float4* So = (float4*)(S + ((size_t)g << 4));
    So[0] = h0; So[1] = h1; So[2] = h2; So[3] = h3;
    sumdt[g] = sdt;
}

__global__ __launch_bounds__(256) void scan_phase2(float* __restrict__ S,
                                                   const float* __restrict__ sumdt,
                                                   const float* __restrict__ A_log) {
    int g = blockIdx.x * 256 + threadIdx.x;  // 65536
    int n = g & 15;
    int c = g >> 4;
    int d = c & (D_INNER - 1);
    float cn = -__expf(A_log[d * D_STATE + n]);
    float h = 0.f;
#pragma unroll 8
    for (int k = 0; k < NC; ++k) {
        int kc = (k << 12) | c;
        float P = __expf(sumdt[kc] * cn);
        size_t o = ((size_t)kc << 4) + n;
        float s = S[o];
        S[o] = h;              // hin for chunk k
        h = P * h + s;
    }
}

__global__ __launch_bounds__(256) void scan_phase3(const ushort* __restrict__ delta,
                                                   const ushort* __restrict__ xc,
                                                   const ushort* __restrict__ dbl,
                                                   const ushort* __restrict__ zb,
                                                   const float* __restrict__ A_log,
                                                   const float* __restrict__ Dp,
                                                   const float* __restrict__ hin,
                                                   ushort* __restrict__ y) {
    __shared__ float bcs[CL][32];
    int tid = threadIdx.x;
    int g = blockIdx.x * 256 + tid;
    int c = g & (NCH - 1);
    int k = g >> 12;
    int d = c & (D_INNER - 1);
    int b = c >> 11;
    size_t r0 = (size_t)b * SEQ + (size_t)k * CL;  // block-uniform

    if (tid < CL * 8) {
        int t = tid >> 3, j = (tid & 7) << 2;
        ushort4 u4 = *(const ushort4*)(dbl + (r0 + t) * 96 + DT_RANK + j);
        bcs[t][j + 0] = bf2f(u4.x); bcs[t][j + 1] = bf2f(u4.y);
        bcs[t][j + 2] = bf2f(u4.z); bcs[t][j + 3] = bf2f(u4.w);
    }

    const float4* al = (const float4*)(A_log + d * D_STATE);
    float4 c0 = al[0], c1 = al[1], c2 = al[2], c3 = al[3];
    c0.x = -__expf(c0.x); c0.y = -__expf(c0.y); c0.z = -__expf(c0.z); c0.w = -__expf(c0.w);
    c1.x = -__expf(c1.x); c1.y = -__expf(c1.y); c1.z = -__expf(c1.z); c1.w = -__expf(c1.w);
    c2.x = -__expf(c2.x); c2.y = -__expf(c2.y); c2.z = -__expf(c2.z); c2.w = -__expf(c2.w);
    c3.x = -__expf(c3.x); c3.y = -__expf(c3.y); c3.z = -__expf(c3.z); c3.w = -__expf(c3.w);
    float Dv = Dp[d];
    const float4* hi = (const float4*)(hin + ((size_t)g << 4));
    float4 h0 = hi[0], h1 = hi[1], h2 = hi[2], h3 = hi[3];
    __syncthreads();

    const ushort* pd = delta + r0 * D_INNER + d;
    const ushort* pu = xc    + r0 * D_INNER + d;
    const ushort* pz = zb    + r0 * D_INNER + d;
    ushort* py = y           + r0 * D_INNER + d;
#pragma unroll 4
    for (int t = 0; t < CL; ++t) {
        float dt = bf2f(*pd), u = bf2f(*pu);
        float4 B0 = *(const float4*)&bcs[t][0];
        float4 B1 = *(const float4*)&bcs[t][4];
        float4 B2 = *(const float4*)&bcs[t][8];
        float4 B3 = *(const float4*)&bcs[t][12];
        float4 C0 = *(const float4*)&bcs[t][16];
        float4 C1 = *(const float4*)&bcs[t][20];
        float4 C2 = *(const float4*)&bcs[t][24];
        float4 C3 = *(const float4*)&bcs[t][28];
        float du = dt * u;
        HUPD(h0, c0, B0) HUPD(h1, c1, B1) HUPD(h2, c2, B2) HUPD(h3, c3, B3)
        float acc = h0.x * C0.x + h0.y * C0.y + h0.z * C0.z + h0.w * C0.w
                  + h1.x * C1.x + h1.y * C1.y + h1.z * C1.z + h1.w * C1.w
                  + h2.x * C2.x + h2.y * C2.y + h2.z * C2.z + h2.w * C2.w
                  + h3.x * C3.x + h3.y * C3.y + h3.z * C3.z + h3.w * C3.w;
        float zv = bf2f(*pz);
        float sz = zv / (1.f + __expf(-zv));
        *py = f2bf((acc + u * Dv) * sz);
        pd += D_INNER; pu += D_INNER; pz += D_INNER; py += D_INNER;
    }
}

extern "C" void kernel_launch(void* const* d_in, const int* in_sizes, int n_in,
                              void* d_out, int out_size, void* d_ws, size_t ws_size,
                              hipStream_t stream) {
    const float* x       = (const float*)d_in[0];
    const float* ln_w    = (const float*)d_in[1];
    const float* ln_b    = (const float*)d_in[2];
    const float* in_proj = (const float*)d_in[3];
    const float* conv_w  = (const float*)d_in[4];
    const float* conv_b  = (const float*)d_in[5];
    const float* x_proj  = (const float*)d_in[6];
    const float* dt_w    = (const float*)d_in[7];
    const float* dt_b    = (const float*)d_in[8];
    const float* A_log   = (const float*)d_in[9];
    const float* Dp      = (const float*)d_in[10];
    const float* out_w   = (const float*)d_in[11];
    float* out = (float*)d_out;

    char* ws = (char*)d_ws;
    const size_t MB = 1024ull * 1024ull;
    // Layout / lifetimes (all intermediates bf16; 128 MB total):
    // [0,8)    xn_bf (LN -> GEMM A)
    // [8,16)   w_in_bf (cvt -> GEMM A)
    // [0,32)   Shin f32 overlay (ph1 -> ph2 -> ph3); valid: xn/w_in dead after
    //          GEMM A; x_in_bf [16,32) dead after conv (ph1 runs later)
    // [16,32)  x_in_bf (GEMM A -> conv)
    // [32,48)  zbuf_bf (GEMM A -> ph3)      (outside Shin)
    // [48,64)  xc_bf (conv -> split, ph1, ph3)
    // [64,65)  dbl_bf 0.75 MB (reduce -> GEMM C, ph1, ph3)
    // [65,66)  dt_w_bf 0.25 MB (cvt -> GEMM C)
    // [66,82)  delta_bf (GEMM C -> ph1, ph3)
    // [82,98)  y_bf (ph3 -> GEMM D)
    // [98,100) sumdt f32 (ph1 -> ph2)
    // [100,124) part f32 24 MB (split -> reduce)
    // [124,128) w_out_bf (cvt -> GEMM D)
    ushort* xn_bf    = (ushort*)(ws);
    ushort* w_in_bf  = (ushort*)(ws + 8 * MB);
    float*  Shin     = (float*)(ws);
    ushort* x_in_bf  = (ushort*)(ws + 16 * MB);
    ushort* zbuf_bf  = (ushort*)(ws + 32 * MB);
    ushort* xc_bf    = (ushort*)(ws + 48 * MB);
    ushort* dbl_bf   = (ushort*)(ws + 64 * MB);
    ushort* dt_w_bf  = (ushort*)(ws + 65 * MB);
    ushort* delta_bf = (ushort*)(ws + 66 * MB);
    ushort* y_bf     = (ushort*)(ws + 82 * MB);
    float*  sumdt    = (float*)(ws + 98 * MB);
    float*  part     = (float*)(ws + 100 * MB);
    ushort* w_out_bf = (ushort*)(ws + 124 * MB);

    // 0. weight converts
    cvt_bf16<<<(2 * D_INNER * D_MODEL / 4) / 256, 256, 0, stream>>>(in_proj, w_in_bf);
    cvt_bf16<<<(D_MODEL * D_INNER / 4) / 256, 256, 0, stream>>>(out_w, w_out_bf);
    cvt_bf16<<<(D_INNER * DT_RANK / 4) / 256, 256, 0, stream>>>(dt_w, dt_w_bf);

    // 1. LayerNorm -> bf16
    ln_kernel<<<NROW, 256, 0, stream>>>(x, ln_w, ln_b, xn_bf);

    // 2. xz = xn @ in_proj^T  -> x_in (bf16) | z (bf16)
    gemm_mfma<0><<<dim3(4096 / 128, NROW / 128), 256, 0, stream>>>(
        xn_bf, D_MODEL, w_in_bf, D_MODEL, nullptr, x_in_bf, zbuf_bf,
        D_INNER, D_INNER, nullptr, D_MODEL);

    // 3. causal depthwise conv + SiLU -> xc (bf16)
    conv_silu<<<(NROW * (D_INNER / 4)) / 256, 256, 0, stream>>>(x_in_bf, conv_w, conv_b, xc_bf);

    // 4. dbl = xc @ x_proj^T  [4096,96] via split-K + reduce (-> bf16)
    gemm_b_split<<<dim3(2, NROW / BM, KSPLIT), 256, 0, stream>>>(xc_bf, x_proj, part);
    gemm_b_reduce<<<(NROW * 96) / 256, 256, 0, stream>>>(part, dbl_bf);

    // 5. delta = softplus(dt @ dt_proj^T + dt_b)  [4096,2048] bf16, MFMA
    gemm_mfma<1><<<dim3(D_INNER / 128, NROW / 128), 256, 0, stream>>>(
        dbl_bf, 96, dt_w_bf, DT_RANK, nullptr, delta_bf, nullptr,
        D_INNER, 0, dt_b, DT_RANK);

    // 6. chunked selective scan (16 states/thread; skip & gate fused in phase 3)
    scan_phase1<<<(NCH * NC) / 256, 256, 0, stream>>>(
        delta_bf, xc_bf, dbl_bf, A_log, Shin, sumdt);
    scan_phase2<<<(NCH * D_STATE) / 256, 256, 0, stream>>>(Shin, sumdt, A_log);
    scan_phase3<<<(NCH * NC) / 256, 256, 0, stream>>>(
        delta_bf, xc_bf, dbl_bf, zbuf_bf, A_log, Dp, Shin, y_bf);

    // 7. out = y @ out_proj^T + x   (bf16 MFMA, residual epilogue)
    gemm_mfma<2><<<dim3(D_MODEL / 128, NROW / 128), 256, 0, stream>>>(
        y_bf, D_INNER, w_out_bf, D_INNER, out, nullptr, nullptr,
        D_MODEL, 0, x, D_INNER);
}

// Round 11
// 389.510 us; speedup vs baseline: 1.1492x; 1.0172x over previous
//
#include <hip/hip_runtime.h>
#include <hip/hip_bf16.h>
#include <math.h>

#define D_MODEL 1024
#define D_INNER 2048
#define DT_RANK 64
#define D_STATE 16
#define BSZ 2
#define SEQ 2048
#define NROW (BSZ * SEQ)    // 4096
#define NC 128              // scan time-chunks
#define CL (SEQ / NC)       // 16 steps per chunk
#define NCH (BSZ * D_INNER) // 4096 scan channels
#define KSPLIT 16           // GEMM B K-split
#define KCH (D_INNER / KSPLIT) // 128
#define DSPLIT 4            // GEMM D K-split

typedef short bf16x8 __attribute__((ext_vector_type(8)));
typedef float f32x4 __attribute__((ext_vector_type(4)));

__device__ inline ushort f2bf(float f) {
    uint32_t u = __float_as_uint(f);
    return (ushort)((u + 0x7FFFu + ((u >> 16) & 1u)) >> 16);
}
__device__ inline float bf2f(ushort u) {
    return __uint_as_float(((uint32_t)u) << 16);
}

__device__ inline void gld_lds16(const void* g, void* l) {
    __builtin_amdgcn_global_load_lds(
        (__attribute__((address_space(1))) void*)g,
        (__attribute__((address_space(3))) void*)l, 16, 0, 0);
}

// ---------------- fused weight converts (3 arrays, 1 dispatch) ----------------
#define CVT_N1 (2 * D_INNER * D_MODEL / 4)   // in_proj f4 count
#define CVT_N2 (D_MODEL * D_INNER / 4)       // out_w
#define CVT_N3 (D_INNER * DT_RANK / 4)       // dt_w
__global__ __launch_bounds__(256) void cvt_all(const float* __restrict__ a,
                                               const float* __restrict__ b,
                                               const float* __restrict__ c,
                                               ushort* __restrict__ oa,
                                               ushort* __restrict__ ob,
                                               ushort* __restrict__ oc) {
    int i = blockIdx.x * 256 + threadIdx.x;
    const float* src; ushort* dst; int j;
    if (i < CVT_N1)               { src = a; dst = oa; j = i; }
    else if (i < CVT_N1 + CVT_N2) { src = b; dst = ob; j = i - CVT_N1; }
    else                          { src = c; dst = oc; j = i - CVT_N1 - CVT_N2; }
    float4 v = ((const float4*)src)[j];
    ushort4 o;
    o.x = f2bf(v.x); o.y = f2bf(v.y); o.z = f2bf(v.z); o.w = f2bf(v.w);
    ((ushort4*)dst)[j] = o;
}

// ---------------- LayerNorm -> bf16 output ----------------
__global__ __launch_bounds__(256) void ln_kernel(const float* __restrict__ x,
                                                 const float* __restrict__ w,
                                                 const float* __restrict__ b,
                                                 ushort* __restrict__ xn) {
    int row = blockIdx.x;
    int tid = threadIdx.x;
    const float4* xr = (const float4*)(x + (size_t)row * D_MODEL);
    float4 v = xr[tid];
    float s  = v.x + v.y + v.z + v.w;
    float ss = v.x * v.x + v.y * v.y + v.z * v.z + v.w * v.w;
#pragma unroll
    for (int o = 32; o > 0; o >>= 1) {
        s  += __shfl_down(s, o);
        ss += __shfl_down(ss, o);
    }
    __shared__ float red[8];
    int wid = tid >> 6, lane = tid & 63;
    if (lane == 0) { red[wid] = s; red[4 + wid] = ss; }
    __syncthreads();
    s  = red[0] + red[1] + red[2] + red[3];
    ss = red[4] + red[5] + red[6] + red[7];
    float mu  = s * (1.0f / D_MODEL);
    float var = ss * (1.0f / D_MODEL) - mu * mu;
    float inv = rsqrtf(var + 1e-5f);
    float4 wv = ((const float4*)w)[tid];
    float4 bv = ((const float4*)b)[tid];
    ushort4 o4;
    o4.x = f2bf((v.x - mu) * inv * wv.x + bv.x);
    o4.y = f2bf((v.y - mu) * inv * wv.y + bv.y);
    o4.z = f2bf((v.z - mu) * inv * wv.z + bv.z);
    o4.w = f2bf((v.w - mu) * inv * wv.w + bv.w);
    ((ushort4*)(xn + (size_t)row * D_MODEL))[tid] = o4;
}

// ---------------- bf16 MFMA GEMM: C = A[M,K] * B[N,K]^T -----------------
// MODE 0: split bf16 store: col<splitN -> Z0, else Z1 (col-splitN), ld=ldc
// MODE 1: Z0 = bf16(softplus(acc + extra[col]))
// MODE 2: C(f32) = acc + extra[row*ldc+col]   (residual)
// MODE 3: K-split partial: A/B offset by blockIdx.z*K, C += z*zstride, f32 store
template <int MODE>
__global__ __launch_bounds__(256) void gemm_mfma(
    const ushort* __restrict__ A, int lda,
    const ushort* __restrict__ B, int ldb,
    float* __restrict__ C, ushort* __restrict__ Z0, ushort* __restrict__ Z1,
    int ldc, int splitN, const float* __restrict__ extra, int K, size_t zstride) {
    __shared__ ushort lds[2][2][128 * 32];
    int tid = threadIdx.x;
    int w = tid >> 6, lane = tid & 63;

    // XCD-aware swizzle (bijective: all grids have nwg % 8 == 0)
    int nwg = gridDim.x * gridDim.y;
    int bid = blockIdx.y * gridDim.x + blockIdx.x;
    int cpx = nwg >> 3;
    int swz = (bid & 7) * cpx + (bid >> 3);
    int bx = swz % gridDim.x, by = swz / gridDim.x;
    int bm = by * 128, bn = bx * 128;
    int wr = w >> 1, wc = w & 1;

    int kofs = (MODE == 3) ? blockIdx.z * K : 0;
    int srow = tid >> 2, sseg = (tid & 3) << 3;
    const ushort* Abase = A + (size_t)(bm + srow) * lda + sseg + kofs;
    const ushort* Bbase = B + (size_t)(bn + srow) * ldb + sseg + kofs;
    int l0 = w * 512;

    int frow = lane & 15, fk = (lane >> 4) << 3;
    f32x4 acc[4][4] = {};

#define STAGE(buf, k0)                                                        \
    do {                                                                      \
        gld_lds16(Abase + (k0),                     &lds[buf][0][l0]);        \
        gld_lds16(Abase + (size_t)64 * lda + (k0),  &lds[buf][0][2048 + l0]); \
        gld_lds16(Bbase + (k0),                     &lds[buf][1][l0]);        \
        gld_lds16(Bbase + (size_t)64 * ldb + (k0),  &lds[buf][1][2048 + l0]); \
    } while (0)

    int nk = K >> 5;
    int cur = 0;
    STAGE(0, 0);
    __syncthreads();
    for (int kt = 0; kt < nk; ++kt) {
        if (kt + 1 < nk) STAGE(cur ^ 1, (kt + 1) << 5);
        bf16x8 a[4], b[4];
#pragma unroll
        for (int m = 0; m < 4; ++m)
            a[m] = *(const bf16x8*)&lds[cur][0][(wr * 64 + m * 16 + frow) * 32 + fk];
#pragma unroll
        for (int n = 0; n < 4; ++n)
            b[n] = *(const bf16x8*)&lds[cur][1][(wc * 64 + n * 16 + frow) * 32 + fk];
#pragma unroll
        for (int m = 0; m < 4; ++m)
#pragma unroll
            for (int n = 0; n < 4; ++n)
                acc[m][n] = __builtin_amdgcn_mfma_f32_16x16x32_bf16(a[m], b[n], acc[m][n], 0, 0, 0);
        __syncthreads();
        cur ^= 1;
    }
#undef STAGE

    float* Cz = (MODE == 3) ? (C + (size_t)blockIdx.z * zstride) : C;
    int rbase = bm + wr * 64 + ((lane >> 4) << 2);
    int cbase = bn + wc * 64 + (lane & 15);
#pragma unroll
    for (int m = 0; m < 4; ++m) {
#pragma unroll
        for (int n = 0; n < 4; ++n) {
            int gc = cbase + n * 16;
#pragma unroll
            for (int j = 0; j < 4; ++j) {
                int gr = rbase + m * 16 + j;
                float v = acc[m][n][j];
                if (MODE == 0) {
                    if (gc < splitN) Z0[(size_t)gr * ldc + gc] = f2bf(v);
                    else             Z1[(size_t)gr * ldc + (gc - splitN)] = f2bf(v);
                } else if (MODE == 1) {
                    v += extra[gc];
                    v = (v > 20.f) ? v : log1pf(__expf(v));
                    Z0[(size_t)gr * ldc + gc] = f2bf(v);
                } else if (MODE == 2) {
                    C[(size_t)gr * ldc + gc] = v + extra[(size_t)gr * ldc + gc];
                } else {
                    Cz[(size_t)gr * ldc + gc] = v;
                }
            }
        }
    }
}

// ---------------- GEMM D reduce: out = x + sum of DSPLIT partials ----------------
__global__ __launch_bounds__(256) void gemm_d_reduce(const float* __restrict__ part,
                                                     const float* __restrict__ x,
                                                     float* __restrict__ out) {
    int i = blockIdx.x * 256 + threadIdx.x;   // over NROW*D_MODEL/4 f4
    float4 s = ((const float4*)x)[i];
#pragma unroll
    for (int z = 0; z < DSPLIT; ++z) {
        float4 p = ((const float4*)(part + (size_t)z * (NROW * D_MODEL)))[i];
        s.x += p.x; s.y += p.y; s.z += p.z; s.w += p.w;
    }
    ((float4*)out)[i] = s;
}

// ---------------- GEMM B split-K: part[kc] = xc_bf[:,kc*128:+128] @ x_proj^T ------
#define BM 64
#define BN 64
#define BK 16
__global__ __launch_bounds__(256) void gemm_b_split(const ushort* __restrict__ A,
                                                    const float* __restrict__ B,
                                                    float* __restrict__ part) {
    __shared__ float As[BK][BM];
    __shared__ float Bs[BK][BN];
    int bm = blockIdx.y * BM, bn = blockIdx.x * BN;
    int kc = blockIdx.z;
    int tid = threadIdx.x;
    int tx = tid & 15, ty = tid >> 4;
    int lrow = tid >> 2, lseg = (tid & 3) << 2;
    float acc[4][4] = {};

    int kbeg = kc * KCH;
    for (int k0 = kbeg; k0 < kbeg + KCH; k0 += BK) {
        ushort4 au = *(const ushort4*)(A + (size_t)(bm + lrow) * D_INNER + k0 + lseg);
        float4 av = make_float4(bf2f(au.x), bf2f(au.y), bf2f(au.z), bf2f(au.w));
        float4 bv = make_float4(0.f, 0.f, 0.f, 0.f);
        int bgr = bn + lrow;
        if (bgr < 96) bv = *(const float4*)(B + (size_t)bgr * D_INNER + k0 + lseg);
        __syncthreads();
        As[lseg + 0][lrow] = av.x; As[lseg + 1][lrow] = av.y;
        As[lseg + 2][lrow] = av.z; As[lseg + 3][lrow] = av.w;
        Bs[lseg + 0][lrow] = bv.x; Bs[lseg + 1][lrow] = bv.y;
        Bs[lseg + 2][lrow] = bv.z; Bs[lseg + 3][lrow] = bv.w;
        __syncthreads();
#pragma unroll
        for (int k = 0; k < BK; ++k) {
            float4 a4 = *(const float4*)&As[k][ty << 2];
            float4 b4 = *(const float4*)&Bs[k][tx << 2];
            float ar[4] = {a4.x, a4.y, a4.z, a4.w};
            float br[4] = {b4.x, b4.y, b4.z, b4.w};
#pragma unroll
            for (int i = 0; i < 4; ++i)
#pragma unroll
                for (int j = 0; j < 4; ++j) acc[i][j] += ar[i] * br[j];
        }
    }

    float* po = part + (size_t)kc * (NROW * 96);
#pragma unroll
    for (int i = 0; i < 4; ++i) {
        int gr = bm + (ty << 2) + i;
#pragma unroll
        for (int j = 0; j < 4; ++j) {
            int gc = bn + (tx << 2) + j;
            if (gc < 96) po[(size_t)gr * 96 + gc] = acc[i][j];
        }
    }
}

__global__ __launch_bounds__(256) void gemm_b_reduce(const float* __restrict__ part,
                                                     ushort* __restrict__ dbl) {
    int i = blockIdx.x * 256 + threadIdx.x;  // 393216
    float s = 0.f;
#pragma unroll
    for (int kc = 0; kc < KSPLIT; ++kc)
        s += part[(size_t)kc * (NROW * 96) + i];
    dbl[i] = f2bf(s);
}

// ---------------- causal depthwise conv1d (k=4) + SiLU, bf16 in/out ---------------
__global__ __launch_bounds__(256) void conv_silu(const ushort* __restrict__ xin,
                                                 const float* __restrict__ w,
                                                 const float* __restrict__ cb,
                                                 ushort* __restrict__ xc) {
    int idx = blockIdx.x * 256 + threadIdx.x;
    int d4 = idx & 511;
    int m  = idx >> 9;
    int l  = m & (SEQ - 1);
    int d  = d4 << 2;
    float4 w0 = ((const float4*)w)[d + 0];
    float4 w1 = ((const float4*)w)[d + 1];
    float4 w2 = ((const float4*)w)[d + 2];
    float4 w3 = ((const float4*)w)[d + 3];
    float wr0[4] = {w0.x, w0.y, w0.z, w0.w};
    float wr1[4] = {w1.x, w1.y, w1.z, w1.w};
    float wr2[4] = {w2.x, w2.y, w2.z, w2.w};
    float wr3[4] = {w3.x, w3.y, w3.z, w3.w};
    float ax = cb[d], ay = cb[d + 1], az = cb[d + 2], aw = cb[d + 3];
#pragma unroll
    for (int j = 0; j < 4; ++j) {
        if (l - 3 + j >= 0) {
            ushort4 xu = *(const ushort4*)(xin + (size_t)(m - 3 + j) * D_INNER + d);
            ax += wr0[j] * bf2f(xu.x);
            ay += wr1[j] * bf2f(xu.y);
            az += wr2[j] * bf2f(xu.z);
            aw += wr3[j] * bf2f(xu.w);
        }
    }
    ushort4 o;
    o.x = f2bf(ax / (1.f + __expf(-ax)));
    o.y = f2bf(ay / (1.f + __expf(-ay)));
    o.z = f2bf(az / (1.f + __expf(-az)));
    o.w = f2bf(aw / (1.f + __expf(-aw)));
    *(ushort4*)(xc + (size_t)m * D_INNER + d) = o;
}

// ---------------- chunked selective scan, 16 states per thread --------------------
#define EXP4(e, cj) \
    e.x = __expf(dt * cj.x); e.y = __expf(dt * cj.y); \
    e.z = __expf(dt * cj.z); e.w = __expf(dt * cj.w);
#define HUPD(hj, cj, Bv) { float4 e; EXP4(e, cj) \
    hj.x = e.x * hj.x + du * Bv.x; hj.y = e.y * hj.y + du * Bv.y; \
    hj.z = e.z * hj.z + du * Bv.z; hj.w = e.w * hj.w + du * Bv.w; }

__global__ __launch_bounds__(256) void scan_phase1(const ushort* __restrict__ delta,
                                                   const ushort* __restrict__ xc,
                                                   const ushort* __restrict__ dbl,
                                                   const float* __restrict__ A_log,
                                                   float* __restrict__ S,
                                                   float* __restrict__ sumdt) {
    __shared__ float bs[CL][16];
    int tid = threadIdx.x;
    int g = blockIdx.x * 256 + tid;   // NCH*NC = 524288
    int c = g & (NCH - 1);
    int k = g >> 12;
    int d = c & (D_INNER - 1);
    int b = c >> 11;
    size_t r0 = (size_t)b * SEQ + (size_t)k * CL;  // block-uniform

    if (tid < CL * 4) {
        int t = tid >> 2, j = (tid & 3) << 2;
        ushort4 u4 = *(const ushort4*)(dbl + (r0 + t) * 96 + DT_RANK + j);
        bs[t][j + 0] = bf2f(u4.x); bs[t][j + 1] = bf2f(u4.y);
        bs[t][j + 2] = bf2f(u4.z); bs[t][j + 3] = bf2f(u4.w);
    }

    const float4* al = (const float4*)(A_log + d * D_STATE);
    float4 c0 = al[0], c1 = al[1], c2 = al[2], c3 = al[3];
    c0.x = -__expf(c0.x); c0.y = -__expf(c0.y); c0.z = -__expf(c0.z); c0.w = -__expf(c0.w);
    c1.x = -__expf(c1.x); c1.y = -__expf(c1.y); c1.z = -__expf(c1.z); c1.w = -__expf(c1.w);
    c2.x = -__expf(c2.x); c2.y = -__expf(c2.y); c2.z = -__expf(c2.z); c2.w = -__expf(c2.w);
    c3.x = -__expf(c3.x); c3.y = -__expf(c3.y); c3.z = -__expf(c3.z); c3.w = -__expf(c3.w);
    __syncthreads();

    const ushort* pd = delta + r0 * D_INNER + d;
    const ushort* pu = xc    + r0 * D_INNER + d;
    float4 h0 = {}, h1 = {}, h2 = {}, h3 = {};
    float sdt = 0.f;
#pragma unroll 4
    for (int t = 0; t < CL; ++t) {
        float dt = bf2f(*pd), u = bf2f(*pu);
        float4 B0 = *(const float4*)&bs[t][0];
        float4 B1 = *(const float4*)&bs[t][4];
        float4 B2 = *(const float4*)&bs[t][8];
        float4 B3 = *(const float4*)&bs[t][12];
        float du = dt * u;
        sdt += dt;
        HUPD(h0, c0, B0) HUPD(h1, c1, B1) HUPD(h2, c2, B2) HUPD(h3, c3, B3)
        pd += D_INNER; pu += D_INNER;
    }
    float4* So = (float4*)(S + ((size_t)g << 4));
    So[0] = h0; So[1] = h1; So[2] = h2; So[3] = h3;
    sumdt[g] = sdt;
}

__global__ __launch_bounds__(256) void scan_phase2(float* __restrict__ S,
                                                   const float* __restrict__ sumdt,
                                                   const float* __restrict__ A_log) {
    int g = blockIdx.x * 256 + threadIdx.x;  // 65536
    int n = g & 15;
    int c = g >> 4;
    int d = c & (D_INNER - 1);
    float cn = -__expf(A_log[d * D_STATE + n]);
    float h = 0.f;
#pragma unroll 8
    for (int k = 0; k < NC; ++k) {
        int kc = (k << 12) | c;
        float P = __expf(sumdt[kc] * cn);
        size_t o = ((size_t)kc << 4) + n;
        float s = S[o];
        S[o] = h;              // hin for chunk k
        h = P * h + s;
    }
}

__global__ __launch_bounds__(256) void scan_phase3(const ushort* __restrict__ delta,
                                                   const ushort* __restrict__ xc,
                                                   const ushort* __restrict__ dbl,
                                                   const ushort* __restrict__ zb,
                                                   const float* __restrict__ A_log,
                                                   const float* __restrict__ Dp,
                                                   const float* __restrict__ hin,
                                                   ushort* __restrict__ y) {
    __shared__ float bcs[CL][32];
    int tid = threadIdx.x;
    int g = blockIdx.x * 256 + tid;
    int c = g & (NCH - 1);
    int k = g >> 12;
    int d = c & (D_INNER - 1);
    int b = c >> 11;
    size_t r0 = (size_t)b * SEQ + (size_t)k * CL;  // block-uniform

    if (tid < CL * 8) {
        int t = tid >> 3, j = (tid & 7) << 2;
        ushort4 u4 = *(const ushort4*)(dbl + (r0 + t) * 96 + DT_RANK + j);
        bcs[t][j + 0] = bf2f(u4.x); bcs[t][j + 1] = bf2f(u4.y);
        bcs[t][j + 2] = bf2f(u4.z); bcs[t][j + 3] = bf2f(u4.w);
    }

    const float4* al = (const float4*)(A_log + d * D_STATE);
    float4 c0 = al[0], c1 = al[1], c2 = al[2], c3 = al[3];
    c0.x = -__expf(c0.x); c0.y = -__expf(c0.y); c0.z = -__expf(c0.z); c0.w = -__expf(c0.w);
    c1.x = -__expf(c1.x); c1.y = -__expf(c1.y); c1.z = -__expf(c1.z); c1.w = -__expf(c1.w);
    c2.x = -__expf(c2.x); c2.y = -__expf(c2.y); c2.z = -__expf(c2.z); c2.w = -__expf(c2.w);
    c3.x = -__expf(c3.x); c3.y = -__expf(c3.y); c3.z = -__expf(c3.z); c3.w = -__expf(c3.w);
    float Dv = Dp[d];
    const float4* hi = (const float4*)(hin + ((size_t)g << 4));
    float4 h0 = hi[0], h1 = hi[1], h2 = hi[2], h3 = hi[3];
    __syncthreads();

    const ushort* pd = delta + r0 * D_INNER + d;
    const ushort* pu = xc    + r0 * D_INNER + d;
    const ushort* pz = zb    + r0 * D_INNER + d;
    ushort* py = y           + r0 * D_INNER + d;
#pragma unroll 4
    for (int t = 0; t < CL; ++t) {
        float dt = bf2f(*pd), u = bf2f(*pu);
        float4 B0 = *(const float4*)&bcs[t][0];
        float4 B1 = *(const float4*)&bcs[t][4];
        float4 B2 = *(const float4*)&bcs[t][8];
        float4 B3 = *(const float4*)&bcs[t][12];
        float4 C0 = *(const float4*)&bcs[t][16];
        float4 C1 = *(const float4*)&bcs[t][20];
        float4 C2 = *(const float4*)&bcs[t][24];
        float4 C3 = *(const float4*)&bcs[t][28];
        float du = dt * u;
        HUPD(h0, c0, B0) HUPD(h1, c1, B1) HUPD(h2, c2, B2) HUPD(h3, c3, B3)
        float acc = h0.x * C0.x + h0.y * C0.y + h0.z * C0.z + h0.w * C0.w
                  + h1.x * C1.x + h1.y * C1.y + h1.z * C1.z + h1.w * C1.w
                  + h2.x * C2.x + h2.y * C2.y + h2.z * C2.z + h2.w * C2.w
                  + h3.x * C3.x + h3.y * C3.y + h3.z * C3.z + h3.w * C3.w;
        float zv = bf2f(*pz);
        float sz = zv / (1.f + __expf(-zv));
        *py = f2bf((acc + u * Dv) * sz);
        pd += D_INNER; pu += D_INNER; pz += D_INNER; py += D_INNER;
    }
}

extern "C" void kernel_launch(void* const* d_in, const int* in_sizes, int n_in,
                              void* d_out, int out_size, void* d_ws, size_t ws_size,
                              hipStream_t stream) {
    const float* x       = (const float*)d_in[0];
    const float* ln_w    = (const float*)d_in[1];
    const float* ln_b    = (const float*)d_in[2];
    const float* in_proj = (const float*)d_in[3];
    const float* conv_w  = (const float*)d_in[4];
    const float* conv_b  = (const float*)d_in[5];
    const float* x_proj  = (const float*)d_in[6];
    const float* dt_w    = (const float*)d_in[7];
    const float* dt_b    = (const float*)d_in[8];
    const float* A_log   = (const float*)d_in[9];
    const float* Dp      = (const float*)d_in[10];
    const float* out_w   = (const float*)d_in[11];
    float* out = (float*)d_out;

    char* ws = (char*)d_ws;
    const size_t MB = 1024ull * 1024ull;
    // Layout / lifetimes (bf16 intermediates; 128 MB):
    // [0,8)    xn_bf (LN -> GEMM A)
    // [8,16)   w_in_bf (cvt -> GEMM A)
    // [0,32)   Shin f32 overlay (ph1 -> ph2 -> ph3)
    // [0,64)   part_d f32 overlay (GEMM D split -> reduce) — all of [0,64) dead
    //          after ph3: xn/w_in (GEMM A), x_in_bf (conv), zbuf (ph3), xc (ph3)
    // [16,32)  x_in_bf (GEMM A -> conv)
    // [32,48)  zbuf_bf (GEMM A -> ph3)
    // [48,64)  xc_bf (conv -> split, ph1, ph3)
    // [64,65)  dbl_bf (reduce -> GEMM C, ph1, ph3)
    // [65,66)  dt_w_bf (cvt -> GEMM C)
    // [66,82)  delta_bf (GEMM C -> ph1, ph3)
    // [82,98)  y_bf (ph3 -> GEMM D)
    // [98,100) sumdt f32 (ph1 -> ph2)
    // [100,124) part_b f32 24 MB (split -> reduce)
    // [124,128) w_out_bf (cvt -> GEMM D)
    ushort* xn_bf    = (ushort*)(ws);
    ushort* w_in_bf  = (ushort*)(ws + 8 * MB);
    float*  Shin     = (float*)(ws);
    float*  part_d   = (float*)(ws);              // 64 MB: [4][4096][1024] f32
    ushort* x_in_bf  = (ushort*)(ws + 16 * MB);
    ushort* zbuf_bf  = (ushort*)(ws + 32 * MB);
    ushort* xc_bf    = (ushort*)(ws + 48 * MB);
    ushort* dbl_bf   = (ushort*)(ws + 64 * MB);
    ushort* dt_w_bf  = (ushort*)(ws + 65 * MB);
    ushort* delta_bf = (ushort*)(ws + 66 * MB);
    ushort* y_bf     = (ushort*)(ws + 82 * MB);
    float*  sumdt    = (float*)(ws + 98 * MB);
    float*  part_b   = (float*)(ws + 100 * MB);
    ushort* w_out_bf = (ushort*)(ws + 124 * MB);

    // 0. fused weight converts (1 dispatch)
    cvt_all<<<(CVT_N1 + CVT_N2 + CVT_N3) / 256, 256, 0, stream>>>(
        in_proj, out_w, dt_w, w_in_bf, w_out_bf, dt_w_bf);

    // 1. LayerNorm -> bf16
    ln_kernel<<<NROW, 256, 0, stream>>>(x, ln_w, ln_b, xn_bf);

    // 2. xz = xn @ in_proj^T  -> x_in (bf16) | z (bf16)
    gemm_mfma<0><<<dim3(4096 / 128, NROW / 128), 256, 0, stream>>>(
        xn_bf, D_MODEL, w_in_bf, D_MODEL, nullptr, x_in_bf, zbuf_bf,
        D_INNER, D_INNER, nullptr, D_MODEL, 0);

    // 3. causal depthwise conv + SiLU -> xc (bf16)
    conv_silu<<<(NROW * (D_INNER / 4)) / 256, 256, 0, stream>>>(x_in_bf, conv_w, conv_b, xc_bf);

    // 4. dbl = xc @ x_proj^T  [4096,96] via split-K + reduce (-> bf16)
    gemm_b_split<<<dim3(2, NROW / BM, KSPLIT), 256, 0, stream>>>(xc_bf, x_proj, part_b);
    gemm_b_reduce<<<(NROW * 96) / 256, 256, 0, stream>>>(part_b, dbl_bf);

    // 5. delta = softplus(dt @ dt_proj^T + dt_b)  [4096,2048] bf16, MFMA
    gemm_mfma<1><<<dim3(D_INNER / 128, NROW / 128), 256, 0, stream>>>(
        dbl_bf, 96, dt_w_bf, DT_RANK, nullptr, delta_bf, nullptr,
        D_INNER, 0, dt_b, DT_RANK, 0);

    // 6. chunked selective scan (16 states/thread; skip & gate fused in phase 3)
    scan_phase1<<<(NCH * NC) / 256, 256, 0, stream>>>(
        delta_bf, xc_bf, dbl_bf, A_log, Shin, sumdt);
    scan_phase2<<<(NCH * D_STATE) / 256, 256, 0, stream>>>(Shin, sumdt, A_log);
    scan_phase3<<<(NCH * NC) / 256, 256, 0, stream>>>(
        delta_bf, xc_bf, dbl_bf, zbuf_bf, A_log, Dp, Shin, y_bf);

    // 7. out = y @ out_proj^T + x   via K-split MFMA partials + residual reduce
    gemm_mfma<3><<<dim3(D_MODEL / 128, NROW / 128, DSPLIT), 256, 0, stream>>>(
        y_bf, D_INNER, w_out_bf, D_INNER, part_d, nullptr, nullptr,
        D_MODEL, 0, nullptr, D_INNER / DSPLIT, (size_t)NROW * D_MODEL);
    gemm_d_reduce<<<(NROW * D_MODEL / 4) / 256, 256, 0, stream>>>(part_d, x, out);
}